// Round 1
// baseline (727.584 us; speedup 1.0000x reference)
//
#include <hip/hip_runtime.h>
#include <hip/hip_bf16.h>
#include <math.h>

typedef __bf16 bf16_t;
typedef __bf16 bf16x8 __attribute__((ext_vector_type(8)));
typedef float  f32x4  __attribute__((ext_vector_type(4)));

#define NROWS 50000

// ---------------- weight conversion ----------------
__global__ void k_convert(const float* __restrict__ fcW,
                          const float* __restrict__ aW,
                          const float* __restrict__ bW,
                          bf16_t* __restrict__ W1b, bf16_t* __restrict__ B2b) {
    int i = blockIdx.x * 256 + threadIdx.x;
    if (i < 524288) W1b[i] = (bf16_t)fcW[i];
    if (i < 262144) {
        int r = i >> 9, k = i & 511;
        int g = r >> 4, u = g >> 1, j = u * 16 + (r & 15);
        const float* src = (g & 1) ? bW : aW;
        B2b[i] = (bf16_t)src[j * 512 + k];
    }
}

// ---------------- GEMM1: hh = relu(x @ fc_W^T + fc_b), bf16 out ----------------
__global__ __launch_bounds__(512) void k_gemm1(
        const float* __restrict__ x, const bf16_t* __restrict__ W1b,
        const float* __restrict__ fcb, bf16_t* __restrict__ hh) {
    __shared__ __align__(16) bf16_t xs[64][40];
    __shared__ __align__(16) bf16_t bs[512][40];
    const int tid = threadIdx.x;
    const int w  = tid >> 6;
    const int l  = tid & 63;
    const int q  = l >> 4;
    const int li = l & 15;
    const long row0 = (long)blockIdx.x * 64;

    f32x4 acc[4][4];
    for (int a = 0; a < 4; a++) for (int b = 0; b < 4; b++) acc[a][b] = (f32x4)0.0f;

    const int rx = tid >> 3;            // x staging: row 0..63
    const int kx = (tid & 7) * 4;       // 4 floats
    const long xrow = row0 + rx;
    const bool xvalid = (xrow < NROWS);
    const float* xp = x + xrow * 1024 + kx;
    const bf16_t* wp = W1b + (long)tid * 1024;

    for (int k0 = 0; k0 < 1024; k0 += 32) {
        __syncthreads();
        // stage x tile (fp32 -> bf16)
        float4 xv = xvalid ? *(const float4*)(xp + k0) : make_float4(0.f, 0.f, 0.f, 0.f);
        union { bf16_t h[4]; uint64_t u; } pk;
        pk.h[0] = (bf16_t)xv.x; pk.h[1] = (bf16_t)xv.y;
        pk.h[2] = (bf16_t)xv.z; pk.h[3] = (bf16_t)xv.w;
        *(uint64_t*)&xs[rx][kx] = pk.u;
        // stage B tile: thread -> W1 row tid, 32 bf16
        const bf16_t* wq = wp + k0;
        bf16x8 b0 = *(const bf16x8*)(wq);
        bf16x8 b1 = *(const bf16x8*)(wq + 8);
        bf16x8 b2 = *(const bf16x8*)(wq + 16);
        bf16x8 b3 = *(const bf16x8*)(wq + 24);
        *(bf16x8*)&bs[tid][0]  = b0;
        *(bf16x8*)&bs[tid][8]  = b1;
        *(bf16x8*)&bs[tid][16] = b2;
        *(bf16x8*)&bs[tid][24] = b3;
        __syncthreads();
        bf16x8 af[4], bfr[4];
        for (int tm = 0; tm < 4; tm++) af[tm]  = *(const bf16x8*)&xs[tm * 16 + li][q * 8];
        for (int tn = 0; tn < 4; tn++) bfr[tn] = *(const bf16x8*)&bs[w * 64 + tn * 16 + li][q * 8];
        for (int tm = 0; tm < 4; tm++)
            for (int tn = 0; tn < 4; tn++)
                acc[tm][tn] = __builtin_amdgcn_mfma_f32_16x16x32_bf16(af[tm], bfr[tn], acc[tm][tn], 0, 0, 0);
    }
    // epilogue: bias + relu + bf16 store
    for (int tn = 0; tn < 4; tn++) {
        int col = w * 64 + tn * 16 + li;
        float bias = fcb[col];
        for (int tm = 0; tm < 4; tm++) {
            for (int r = 0; r < 4; r++) {
                long row = row0 + tm * 16 + q * 4 + r;
                if (row < NROWS) {
                    float v = acc[tm][tn][r] + bias;
                    v = v > 0.f ? v : 0.f;
                    hh[row * 512 + col] = (bf16_t)v;
                }
            }
        }
    }
}

// ---------------- GEMM2: a|b interleaved, fused tanh*sigmoid*att_c -> A_raw ----------------
__global__ __launch_bounds__(512) void k_gemm2(
        const bf16_t* __restrict__ hh, const bf16_t* __restrict__ B2b,
        const float* __restrict__ aab, const float* __restrict__ abb,
        const float* __restrict__ acW, const float* __restrict__ acb,
        float* __restrict__ Araw) {
    __shared__ __align__(16) bf16_t xs[64][40];
    __shared__ __align__(16) bf16_t bs[512][40];
    __shared__ float partial[64][9];
    const int tid = threadIdx.x;
    const int w  = tid >> 6;
    const int l  = tid & 63;
    const int q  = l >> 4;
    const int li = l & 15;
    const long row0 = (long)blockIdx.x * 64;

    f32x4 acc[4][4];
    for (int a = 0; a < 4; a++) for (int b = 0; b < 4; b++) acc[a][b] = (f32x4)0.0f;

    const bf16_t* bp = B2b + (long)tid * 512;

    for (int k0 = 0; k0 < 512; k0 += 32) {
        __syncthreads();
        if (tid < 256) {
            int r = tid >> 2, kc = (tid & 3) * 8;
            long row = row0 + r;
            bf16x8 hv;
            if (row < NROWS) hv = *(const bf16x8*)(hh + row * 512 + k0 + kc);
            else             hv = (bf16x8)(bf16_t)0.f;
            *(bf16x8*)&xs[r][kc] = hv;
        }
        const bf16_t* bq = bp + k0;
        bf16x8 b0 = *(const bf16x8*)(bq);
        bf16x8 b1 = *(const bf16x8*)(bq + 8);
        bf16x8 b2 = *(const bf16x8*)(bq + 16);
        bf16x8 b3 = *(const bf16x8*)(bq + 24);
        *(bf16x8*)&bs[tid][0]  = b0;
        *(bf16x8*)&bs[tid][8]  = b1;
        *(bf16x8*)&bs[tid][16] = b2;
        *(bf16x8*)&bs[tid][24] = b3;
        __syncthreads();
        bf16x8 af[4], bfr[4];
        for (int tm = 0; tm < 4; tm++) af[tm]  = *(const bf16x8*)&xs[tm * 16 + li][q * 8];
        for (int tn = 0; tn < 4; tn++) bfr[tn] = *(const bf16x8*)&bs[w * 64 + tn * 16 + li][q * 8];
        for (int tm = 0; tm < 4; tm++)
            for (int tn = 0; tn < 4; tn++)
                acc[tm][tn] = __builtin_amdgcn_mfma_f32_16x16x32_bf16(af[tm], bfr[tn], acc[tm][tn], 0, 0, 0);
    }
    // epilogue: per-lane pair (a,b), reduce over 256-dim att axis
    float sum_mr[4][4];
    for (int a = 0; a < 4; a++) for (int b = 0; b < 4; b++) sum_mr[a][b] = 0.f;
    for (int p = 0; p < 2; p++) {
        int j = (w * 2 + p) * 16 + li;
        float ab_ = aab[j], bb_ = abb[j], cw = acW[j];
        int tn_a = p * 2, tn_b = p * 2 + 1;
        for (int tm = 0; tm < 4; tm++) {
            for (int r = 0; r < 4; r++) {
                float av = tanhf(acc[tm][tn_a][r] + ab_);
                float bv = acc[tm][tn_b][r] + bb_;
                bv = 1.f / (1.f + expf(-bv));
                sum_mr[tm][r] += av * bv * cw;
            }
        }
    }
    for (int tm = 0; tm < 4; tm++) {
        for (int r = 0; r < 4; r++) {
            float v = sum_mr[tm][r];
            v += __shfl_xor(v, 1); v += __shfl_xor(v, 2);
            v += __shfl_xor(v, 4); v += __shfl_xor(v, 8);
            if (li == 0) partial[tm * 16 + q * 4 + r][w] = v;
        }
    }
    __syncthreads();
    if (tid < 64) {
        float s = acb[0];
        for (int ww = 0; ww < 8; ww++) s += partial[tid][ww];
        long row = row0 + tid;
        if (row < NROWS) Araw[row] = s;
    }
}

// ---------------- instance_scores = hh @ cls_W^T + cls_b ----------------
__global__ __launch_bounds__(256) void k_cls(
        const bf16_t* __restrict__ hh, const float* __restrict__ clsW,
        const float* __restrict__ clsb, float* __restrict__ out) {
    long row = (long)((blockIdx.x * 256 + threadIdx.x) >> 6);
    int l = threadIdx.x & 63;
    bf16x8 hv = *(const bf16x8*)(hh + row * 512 + l * 8);
    const float* w0 = clsW + l * 8;
    const float* w1 = clsW + 512 + l * 8;
    float s0 = 0.f, s1 = 0.f;
    for (int j = 0; j < 8; j++) {
        float h = (float)hv[j];
        s0 += h * w0[j]; s1 += h * w1[j];
    }
    for (int m = 1; m < 64; m <<= 1) { s0 += __shfl_xor(s0, m); s1 += __shfl_xor(s1, m); }
    if (l == 0) {
        out[row * 2 + 0] = s0 + clsb[0];
        out[row * 2 + 1] = s1 + clsb[1];
    }
}

// ---------------- softmax stats ----------------
__global__ void k_max(const float* __restrict__ Araw, float* partmax, float* sums) {
    __shared__ float wmax[4];
    int tid = threadIdx.x;
    float m = -1e30f;
    for (int i = blockIdx.x * 256 + tid; i < NROWS; i += 32768) m = fmaxf(m, Araw[i]);
    for (int s = 1; s < 64; s <<= 1) m = fmaxf(m, __shfl_xor(m, s));
    if ((tid & 63) == 0) wmax[tid >> 6] = m;
    __syncthreads();
    if (tid == 0) {
        partmax[blockIdx.x] = fmaxf(fmaxf(wmax[0], wmax[1]), fmaxf(wmax[2], wmax[3]));
        if (blockIdx.x == 0) { sums[0] = 0.f; sums[1] = 0.f; sums[2] = 0.f; }
    }
}

__global__ void k_sum(const float* __restrict__ Araw, const float* __restrict__ inst,
                      const float* __restrict__ partmax, float* sums) {
    __shared__ float rm[4], r0[4], r1[4], r2[4];
    int tid = threadIdx.x;
    float m = partmax[tid & 127];
    for (int s = 1; s < 64; s <<= 1) m = fmaxf(m, __shfl_xor(m, s));
    if ((tid & 63) == 0) rm[tid >> 6] = m;
    __syncthreads();
    float mx = fmaxf(fmaxf(rm[0], rm[1]), fmaxf(rm[2], rm[3]));
    float se = 0.f, s0 = 0.f, s1 = 0.f;
    for (int i = blockIdx.x * 256 + tid; i < NROWS; i += 32768) {
        float e = expf(Araw[i] - mx);
        se += e; s0 += inst[2 * i] * e; s1 += inst[2 * i + 1] * e;
    }
    for (int s = 1; s < 64; s <<= 1) {
        se += __shfl_xor(se, s); s0 += __shfl_xor(s0, s); s1 += __shfl_xor(s1, s);
    }
    if ((tid & 63) == 0) { r0[tid >> 6] = se; r1[tid >> 6] = s0; r2[tid >> 6] = s1; }
    __syncthreads();
    if (tid == 0) {
        atomicAdd(&sums[0], r0[0] + r0[1] + r0[2] + r0[3]);
        atomicAdd(&sums[1], r1[0] + r1[1] + r1[2] + r1[3]);
        atomicAdd(&sums[2], r2[0] + r2[1] + r2[2] + r2[3]);
    }
}

// ---------------- top-8 / bottom-8 with JAX tie-break (lower idx wins) ----------------
__global__ void k_topk(const float* __restrict__ scores, int* __restrict__ ids) {
    __shared__ float cv[4096];
    __shared__ int   ci[4096];
    __shared__ float bwv[8]; __shared__ int bwi[8]; __shared__ int bws[8];
    int tid = threadIdx.x; // 512 threads
    for (int pass = 0; pass < 2; pass++) {
        float sign = (pass == 0) ? 1.f : -1.f;
        float tv[8]; int ti[8];
        for (int k = 0; k < 8; k++) { tv[k] = -1e30f; ti[k] = 0x7fffffff; }
        for (int i = tid; i < NROWS; i += 512) {
            float v = sign * scores[i];
            if (v > tv[7] || (v == tv[7] && i < ti[7])) {
                int k = 7;
                while (k > 0 && (v > tv[k-1] || (v == tv[k-1] && i < ti[k-1]))) {
                    tv[k] = tv[k-1]; ti[k] = ti[k-1]; k--;
                }
                tv[k] = v; ti[k] = i;
            }
        }
        for (int k = 0; k < 8; k++) { cv[tid * 8 + k] = tv[k]; ci[tid * 8 + k] = ti[k]; }
        __syncthreads();
        for (int r = 0; r < 8; r++) {
            float bv = -1e30f; int bi = 0x7fffffff, bslot = 0;
            for (int j = 0; j < 8; j++) {
                int s = tid + 512 * j;
                float v = cv[s]; int idx = ci[s];
                if (v > bv || (v == bv && idx < bi)) { bv = v; bi = idx; bslot = s; }
            }
            for (int m = 1; m < 64; m <<= 1) {
                float ov = __shfl_xor(bv, m); int oi = __shfl_xor(bi, m); int os = __shfl_xor(bslot, m);
                if (ov > bv || (ov == bv && oi < bi)) { bv = ov; bi = oi; bslot = os; }
            }
            if ((tid & 63) == 0) { bwv[tid >> 6] = bv; bwi[tid >> 6] = bi; bws[tid >> 6] = bslot; }
            __syncthreads();
            if (tid == 0) {
                float BV = -1e30f; int BI = 0x7fffffff, BS = 0;
                for (int wv = 0; wv < 8; wv++) {
                    if (bwv[wv] > BV || (bwv[wv] == BV && bwi[wv] < BI)) { BV = bwv[wv]; BI = bwi[wv]; BS = bws[wv]; }
                }
                ids[pass * 8 + r] = BI;
                cv[BS] = -1e30f; ci[BS] = 0x7fffffff;
            }
            __syncthreads();
        }
        __syncthreads();
    }
}

// ---------------- finalize: preds + instance_loss ----------------
__global__ void k_fin(const bf16_t* __restrict__ hh, const int* __restrict__ ids,
                      const float* __restrict__ sums, const float* __restrict__ instW,
                      const float* __restrict__ instb, float* __restrict__ dout) {
    __shared__ float lg[16][2];
    int tid = threadIdx.x;          // 256 threads
    int r  = tid >> 4;              // 16 rows
    int li = tid & 15;
    int id = ids[r];
    const bf16_t* hp = hh + (long)id * 512;
    float p0 = 0.f, p1 = 0.f;
    for (int k = li * 32; k < li * 32 + 32; k++) {
        float h = (float)hp[k];
        p0 += h * instW[k]; p1 += h * instW[512 + k];
    }
    for (int m = 1; m < 16; m <<= 1) { p0 += __shfl_xor(p0, m); p1 += __shfl_xor(p1, m); }
    if (li == 0) { lg[r][0] = p0 + instb[0]; lg[r][1] = p1 + instb[1]; }
    __syncthreads();
    if (tid == 0) {
        float loss = 0.f;
        for (int r2 = 0; r2 < 16; r2++) {
            float l0 = lg[r2][0], l1 = lg[r2][1];
            float mx = fmaxf(l0, l1);
            float lse = mx + logf(expf(l0 - mx) + expf(l1 - mx));
            float lt = (r2 < 8) ? l1 : l0;
            loss += (lse - lt);
        }
        dout[150002] = loss / 16.f;
        float se = sums[0];
        dout[0] = sums[1] / se;
        dout[1] = sums[2] / se;
    }
}

extern "C" void kernel_launch(void* const* d_in, const int* in_sizes, int n_in,
                              void* d_out, int out_size, void* d_ws, size_t ws_size,
                              hipStream_t stream) {
    const float* h   = (const float*)d_in[0];
    const float* fcW = (const float*)d_in[1];
    const float* fcb = (const float*)d_in[2];
    const float* aaW = (const float*)d_in[3];
    const float* aab = (const float*)d_in[4];
    const float* abW = (const float*)d_in[5];
    const float* abb = (const float*)d_in[6];
    const float* acW = (const float*)d_in[7];
    const float* acb = (const float*)d_in[8];
    const float* clW = (const float*)d_in[9];
    const float* clb = (const float*)d_in[10];
    const float* inW = (const float*)d_in[11];
    const float* inb = (const float*)d_in[12];
    float* out = (float*)d_out;

    char* ws = (char*)d_ws;
    bf16_t* hh      = (bf16_t*)(ws);                       // 51,200,000 B
    bf16_t* W1b     = (bf16_t*)(ws + 51200000);            // 1,048,576 B
    bf16_t* B2b     = (bf16_t*)(ws + 52248576);            // 524,288 B
    float*  partmax = (float*) (ws + 52772864);            // 512 B
    float*  sums    = (float*) (ws + 52773888);            // 12 B
    int*    ids     = (int*)   (ws + 52774144);            // 64 B

    float* inst = out + 2;
    float* Araw = out + 2 + 100000;

    k_convert<<<2048, 256, 0, stream>>>(fcW, aaW, abW, W1b, B2b);
    k_gemm1<<<782, 512, 0, stream>>>(h, W1b, fcb, hh);
    k_gemm2<<<782, 512, 0, stream>>>(hh, B2b, aab, abb, acW, acb, Araw);
    k_cls<<<12500, 256, 0, stream>>>(hh, clW, clb, inst);
    k_max<<<128, 256, 0, stream>>>(Araw, partmax, sums);
    k_sum<<<128, 256, 0, stream>>>(Araw, inst, partmax, sums);
    k_topk<<<1, 512, 0, stream>>>(Araw, ids);
    k_fin<<<1, 256, 0, stream>>>(hh, ids, sums, inW, inb, out);
}

// Round 2
// 587.653 us; speedup vs baseline: 1.2381x; 1.2381x over previous
//
#include <hip/hip_runtime.h>
#include <hip/hip_bf16.h>
#include <math.h>

typedef __bf16 bf16_t;
typedef __bf16 bf16x8 __attribute__((ext_vector_type(8)));
typedef float  f32x4  __attribute__((ext_vector_type(4)));

#define NROWS 50000

typedef const __attribute__((address_space(1))) unsigned int* gp_t;
typedef __attribute__((address_space(3))) unsigned int* lp_t;
__device__ __forceinline__ void cp16(void* l, const void* g) {
    __builtin_amdgcn_global_load_lds((gp_t)g, (lp_t)l, 16, 0, 0);
}

// ---------------- weight permutation ----------------
// permW1[kt 0..31][q 0..3][row 0..511][8]  = fcW[row][kt*32+q*8+i]   (bf16)
// permB2[kt 0..15][q 0..3][row 0..511][8]  = interleaved a/b W rows  (bf16)
__global__ void k_convert(const float* __restrict__ fcW,
                          const float* __restrict__ aW,
                          const float* __restrict__ bW,
                          bf16_t* __restrict__ permW1, bf16_t* __restrict__ permB2) {
    int t = blockIdx.x * 256 + threadIdx.x;   // 65536 total
    {
        int row = t & 511, q = (t >> 9) & 3, kt = t >> 11;
        const float* src = fcW + (long)row * 1024 + kt * 32 + q * 8;
        bf16_t o[8];
        #pragma unroll
        for (int i = 0; i < 8; i++) o[i] = (bf16_t)src[i];
        *(bf16x8*)(permW1 + (long)t * 8) = *(bf16x8*)o;
    }
    if (t < 32768) {
        int row = t & 511, q = (t >> 9) & 3, kt = t >> 11;
        int g = row >> 4, u = g >> 1, j = u * 16 + (row & 15);
        const float* src = ((g & 1) ? bW : aW) + (long)j * 512 + kt * 32 + q * 8;
        bf16_t o[8];
        #pragma unroll
        for (int i = 0; i < 8; i++) o[i] = (bf16_t)src[i];
        *(bf16x8*)(permB2 + (long)t * 8) = *(bf16x8*)o;
    }
}

// ---------------- GEMM1: hh = relu(x @ fc_W^T + fc_b), bf16 out ----------------
__global__ __launch_bounds__(512, 4) void k_gemm1(
        const float* __restrict__ x, const bf16_t* __restrict__ permW1,
        const float* __restrict__ fcb, bf16_t* __restrict__ hh) {
    __shared__ __align__(16) char smem[37888];
    bf16_t* bs  = (bf16_t*)smem;              // LDS elem addr: q*4096 + row*8 (32KB)
    bf16_t* xs  = (bf16_t*)(smem + 32768);    // [64][40] padded (5120B)
    bf16_t* t16 = (bf16_t*)smem;              // epilogue overlay: [16][520]

    const int tid = threadIdx.x;
    const int w  = tid >> 6;
    const int l  = tid & 63;
    const int q  = l >> 4;
    const int li = l & 15;
    const long row0 = (long)blockIdx.x * 64;

    f32x4 acc[4][4];
    #pragma unroll
    for (int a = 0; a < 4; a++)
        #pragma unroll
        for (int b = 0; b < 4; b++) acc[a][b] = (f32x4)0.0f;

    const int rx = tid >> 3;            // x staging row 0..63
    const int kx = (tid & 7) * 4;       // 4 floats
    const long xrow = row0 + rx;
    const bool xvalid = (xrow < NROWS);
    const float* xp = x + xrow * 1024 + kx;

    float4 xv = xvalid ? *(const float4*)xp : make_float4(0.f, 0.f, 0.f, 0.f);

    for (int kt = 0; kt < 32; kt++) {
        __syncthreads();
        // --- async W tile: 4 x 16B per thread, fully coalesced ---
        const bf16_t* gw = permW1 + ((long)kt * 2048 + tid) * 8;
        #pragma unroll
        for (int j = 0; j < 4; j++)
            cp16((char*)bs + (j * 512 + tid) * 16, (const char*)(gw + j * 4096));
        // --- x tile from prefetched regs (fp32 -> bf16) ---
        union { bf16_t h[4]; unsigned long long u; } pk;
        pk.h[0] = (bf16_t)xv.x; pk.h[1] = (bf16_t)xv.y;
        pk.h[2] = (bf16_t)xv.z; pk.h[3] = (bf16_t)xv.w;
        *(unsigned long long*)&xs[rx * 40 + kx] = pk.u;
        __syncthreads();
        // --- prefetch next x tile during compute phase ---
        int kn = (kt < 31 ? kt + 1 : 31) * 32;
        xv = xvalid ? *(const float4*)(xp + kn) : make_float4(0.f, 0.f, 0.f, 0.f);
        // --- fragments + MFMA ---
        bf16x8 bfr[4];
        #pragma unroll
        for (int tn = 0; tn < 4; tn++)
            bfr[tn] = *(const bf16x8*)(bs + q * 4096 + (w * 64 + tn * 16 + li) * 8);
        #pragma unroll
        for (int tm = 0; tm < 4; tm++) {
            bf16x8 af = *(const bf16x8*)(xs + (tm * 16 + li) * 40 + q * 8);
            #pragma unroll
            for (int tn = 0; tn < 4; tn++)
                acc[tm][tn] = __builtin_amdgcn_mfma_f32_16x16x32_bf16(af, bfr[tn], acc[tm][tn], 0, 0, 0);
        }
    }
    // ---- epilogue: bias+relu, LDS transpose, coalesced bf16x16 stores ----
    float bias[4];
    #pragma unroll
    for (int tn = 0; tn < 4; tn++) bias[tn] = fcb[w * 64 + tn * 16 + li];

    const int rr = tid >> 5;          // 0..15
    const int cc = tid & 31;          // 32B chunk
    #pragma unroll
    for (int tm = 0; tm < 4; tm++) {
        __syncthreads();
        #pragma unroll
        for (int tn = 0; tn < 4; tn++) {
            int col = w * 64 + tn * 16 + li;
            #pragma unroll
            for (int r = 0; r < 4; r++) {
                float v = acc[tm][tn][r] + bias[tn];
                v = v > 0.f ? v : 0.f;
                t16[(q * 4 + r) * 520 + col] = (bf16_t)v;
            }
        }
        __syncthreads();
        long row = row0 + tm * 16 + rr;
        if (row < NROWS) {
            bf16x8 v0 = *(const bf16x8*)&t16[rr * 520 + cc * 16];
            bf16x8 v1 = *(const bf16x8*)&t16[rr * 520 + cc * 16 + 8];
            *(bf16x8*)&hh[row * 512 + cc * 16] = v0;
            *(bf16x8*)&hh[row * 512 + cc * 16 + 8] = v1;
        }
    }
}

// ---------------- GEMM2: fused att(a,b,c)->Araw  +  cls -> instance_scores ----------------
__global__ __launch_bounds__(512, 4) void k_gemm2(
        const bf16_t* __restrict__ hh, const bf16_t* __restrict__ permB2,
        const float* __restrict__ aab, const float* __restrict__ abb,
        const float* __restrict__ acW, const float* __restrict__ acb,
        const float* __restrict__ clsW, const float* __restrict__ clsb,
        float* __restrict__ Araw, float* __restrict__ inst) {
    __shared__ __align__(16) char smem[36864];
    bf16_t* as = (bf16_t*)smem;               // [64 rows][32k] (4KB)
    bf16_t* bs = (bf16_t*)(smem + 4096);      // q*4096 + row*8 (32KB)
    __shared__ bf16_t cls_lds[1024];          // [2][512]
    __shared__ float apart[64][9];
    __shared__ float cls_part[8][64][2];

    const int tid = threadIdx.x;
    const int w  = tid >> 6;
    const int l  = tid & 63;
    const int q  = l >> 4;
    const int li = l & 15;
    const long row0 = (long)blockIdx.x * 64;

    // stage cls weights once (bf16)
    if (tid < 128) {
        int c = tid >> 6, k8 = (tid & 63) * 8;
        #pragma unroll
        for (int i = 0; i < 8; i++)
            cls_lds[c * 512 + k8 + i] = (bf16_t)clsW[c * 512 + k8 + i];
    }

    f32x4 acc[4][4];
    #pragma unroll
    for (int a = 0; a < 4; a++)
        #pragma unroll
        for (int b = 0; b < 4; b++) acc[a][b] = (f32x4)0.0f;
    float cls0[4] = {0.f,0.f,0.f,0.f}, cls1[4] = {0.f,0.f,0.f,0.f};

    for (int kt = 0; kt < 16; kt++) {
        __syncthreads();
        const bf16_t* gb = permB2 + ((long)kt * 2048 + tid) * 8;
        #pragma unroll
        for (int j = 0; j < 4; j++)
            cp16((char*)bs + (j * 512 + tid) * 16, (const char*)(gb + j * 4096));
        if (tid < 256) {   // A tile: 64 rows x 32k bf16 = 4KB
            const bf16_t* ga = hh + (row0 + (tid >> 2)) * 512 + kt * 32 + (tid & 3) * 8;
            cp16((char*)as + tid * 16, (const char*)ga);
        }
        __syncthreads();
        bf16x8 bfr[4];
        #pragma unroll
        for (int tn = 0; tn < 4; tn++)
            bfr[tn] = *(const bf16x8*)(bs + q * 4096 + (w * 64 + tn * 16 + li) * 8);
        const bool mycls = ((kt >> 1) == w);
        bf16x8 w0, w1;
        if (mycls) {
            w0 = *(const bf16x8*)&cls_lds[kt * 32 + q * 8];
            w1 = *(const bf16x8*)&cls_lds[512 + kt * 32 + q * 8];
        }
        #pragma unroll
        for (int tm = 0; tm < 4; tm++) {
            bf16x8 af = *(const bf16x8*)(as + (tm * 16 + li) * 32 + q * 8);
            #pragma unroll
            for (int tn = 0; tn < 4; tn++)
                acc[tm][tn] = __builtin_amdgcn_mfma_f32_16x16x32_bf16(af, bfr[tn], acc[tm][tn], 0, 0, 0);
            if (mycls) {
                float s0 = 0.f, s1 = 0.f;
                #pragma unroll
                for (int jj = 0; jj < 8; jj++) {
                    float a = (float)af[jj];
                    s0 += a * (float)w0[jj];
                    s1 += a * (float)w1[jj];
                }
                cls0[tm] += s0; cls1[tm] += s1;
            }
        }
    }
    // ---- attention epilogue: tanh*sigmoid*acW, reduce 512 -> Araw ----
    float sum_mr[4][4];
    #pragma unroll
    for (int a = 0; a < 4; a++)
        #pragma unroll
        for (int b = 0; b < 4; b++) sum_mr[a][b] = 0.f;
    #pragma unroll
    for (int p = 0; p < 2; p++) {
        int j = (w * 2 + p) * 16 + li;
        float ab_ = aab[j], bb_ = abb[j], cw = acW[j];
        int tn_a = p * 2, tn_b = p * 2 + 1;
        #pragma unroll
        for (int tm = 0; tm < 4; tm++)
            #pragma unroll
            for (int r = 0; r < 4; r++) {
                float av = tanhf(acc[tm][tn_a][r] + ab_);
                float bv = acc[tm][tn_b][r] + bb_;
                bv = 1.f / (1.f + expf(-bv));
                sum_mr[tm][r] += av * bv * cw;
            }
    }
    #pragma unroll
    for (int tm = 0; tm < 4; tm++)
        #pragma unroll
        for (int r = 0; r < 4; r++) {
            float v = sum_mr[tm][r];
            v += __shfl_xor(v, 1); v += __shfl_xor(v, 2);
            v += __shfl_xor(v, 4); v += __shfl_xor(v, 8);
            if (li == 0) apart[tm * 16 + q * 4 + r][w] = v;
        }
    // ---- cls epilogue: reduce q slices then waves ----
    #pragma unroll
    for (int tm = 0; tm < 4; tm++) {
        cls0[tm] += __shfl_xor(cls0[tm], 16); cls0[tm] += __shfl_xor(cls0[tm], 32);
        cls1[tm] += __shfl_xor(cls1[tm], 16); cls1[tm] += __shfl_xor(cls1[tm], 32);
        if (q == 0) {
            cls_part[w][tm * 16 + li][0] = cls0[tm];
            cls_part[w][tm * 16 + li][1] = cls1[tm];
        }
    }
    __syncthreads();
    if (tid < 64) {
        float s = acb[0];
        #pragma unroll
        for (int ww = 0; ww < 8; ww++) s += apart[tid][ww];
        long row = row0 + tid;
        if (row < NROWS) Araw[row] = s;
    }
    if (tid < 128) {
        int rr = tid >> 1, c = tid & 1;
        float s = clsb[c];
        #pragma unroll
        for (int ww = 0; ww < 8; ww++) s += cls_part[ww][rr][c];
        long row = row0 + rr;
        if (row < NROWS) inst[row * 2 + c] = s;
    }
}

// ---------------- top-8 / bottom-8 (JAX tie-break: lower idx wins), 2 blocks ----------------
__global__ void k_topk(const float* __restrict__ scores, int* __restrict__ ids,
                       float* __restrict__ sums) {
    __shared__ float cv[4096];
    __shared__ int   ci[4096];
    __shared__ float bwv[8]; __shared__ int bwi[8]; __shared__ int bws[8];
    int tid = threadIdx.x;        // 512 threads
    int pass = blockIdx.x;        // 0: top, 1: bottom
    if (pass == 0 && tid == 0) { sums[0] = 0.f; sums[1] = 0.f; sums[2] = 0.f; }
    float sign = (pass == 0) ? 1.f : -1.f;
    float tv[8]; int ti[8];
    #pragma unroll
    for (int k = 0; k < 8; k++) { tv[k] = -1e30f; ti[k] = 0x7fffffff; }
    for (int i = tid; i < NROWS; i += 512) {
        float v = sign * scores[i];
        if (v > tv[7] || (v == tv[7] && i < ti[7])) {
            int k = 7;
            while (k > 0 && (v > tv[k-1] || (v == tv[k-1] && i < ti[k-1]))) {
                tv[k] = tv[k-1]; ti[k] = ti[k-1]; k--;
            }
            tv[k] = v; ti[k] = i;
        }
    }
    for (int k = 0; k < 8; k++) { cv[tid * 8 + k] = tv[k]; ci[tid * 8 + k] = ti[k]; }
    __syncthreads();
    for (int r = 0; r < 8; r++) {
        float bv = -1e30f; int bi = 0x7fffffff, bslot = 0;
        for (int j = 0; j < 8; j++) {
            int s = tid + 512 * j;
            float v = cv[s]; int idx = ci[s];
            if (v > bv || (v == bv && idx < bi)) { bv = v; bi = idx; bslot = s; }
        }
        for (int m = 1; m < 64; m <<= 1) {
            float ov = __shfl_xor(bv, m); int oi = __shfl_xor(bi, m); int os = __shfl_xor(bslot, m);
            if (ov > bv || (ov == bv && oi < bi)) { bv = ov; bi = oi; bslot = os; }
        }
        if ((tid & 63) == 0) { bwv[tid >> 6] = bv; bwi[tid >> 6] = bi; bws[tid >> 6] = bslot; }
        __syncthreads();
        if (tid == 0) {
            float BV = -1e30f; int BI = 0x7fffffff, BS = 0;
            for (int wv = 0; wv < 8; wv++) {
                if (bwv[wv] > BV || (bwv[wv] == BV && bwi[wv] < BI)) { BV = bwv[wv]; BI = bwi[wv]; BS = bws[wv]; }
            }
            ids[pass * 8 + r] = BI;
            cv[BS] = -1e30f; ci[BS] = 0x7fffffff;
        }
        __syncthreads();
    }
}

// ---------------- softmax-weighted sums (max taken from top-1) ----------------
__global__ void k_sum(const float* __restrict__ Araw, const float* __restrict__ inst,
                      const int* __restrict__ ids, float* sums) {
    __shared__ float r0[4], r1[4], r2[4];
    int tid = threadIdx.x;
    float mx = Araw[ids[0]];
    float se = 0.f, s0 = 0.f, s1 = 0.f;
    for (int i = blockIdx.x * 256 + tid; i < NROWS; i += 32768) {
        float e = expf(Araw[i] - mx);
        se += e; s0 += inst[2 * i] * e; s1 += inst[2 * i + 1] * e;
    }
    for (int s = 1; s < 64; s <<= 1) {
        se += __shfl_xor(se, s); s0 += __shfl_xor(s0, s); s1 += __shfl_xor(s1, s);
    }
    if ((tid & 63) == 0) { r0[tid >> 6] = se; r1[tid >> 6] = s0; r2[tid >> 6] = s1; }
    __syncthreads();
    if (tid == 0) {
        atomicAdd(&sums[0], r0[0] + r0[1] + r0[2] + r0[3]);
        atomicAdd(&sums[1], r1[0] + r1[1] + r1[2] + r1[3]);
        atomicAdd(&sums[2], r2[0] + r2[1] + r2[2] + r2[3]);
    }
}

// ---------------- finalize: preds + instance_loss ----------------
__global__ void k_fin(const bf16_t* __restrict__ hh, const int* __restrict__ ids,
                      const float* __restrict__ sums, const float* __restrict__ instW,
                      const float* __restrict__ instb, float* __restrict__ dout) {
    __shared__ float lg[16][2];
    int tid = threadIdx.x;          // 256 threads
    int r  = tid >> 4;              // 16 rows
    int li = tid & 15;
    int id = ids[r];
    const bf16_t* hp = hh + (long)id * 512;
    float p0 = 0.f, p1 = 0.f;
    for (int k = li * 32; k < li * 32 + 32; k++) {
        float h = (float)hp[k];
        p0 += h * instW[k]; p1 += h * instW[512 + k];
    }
    for (int m = 1; m < 16; m <<= 1) { p0 += __shfl_xor(p0, m); p1 += __shfl_xor(p1, m); }
    if (li == 0) { lg[r][0] = p0 + instb[0]; lg[r][1] = p1 + instb[1]; }
    __syncthreads();
    if (tid == 0) {
        float loss = 0.f;
        for (int r2 = 0; r2 < 16; r2++) {
            float l0 = lg[r2][0], l1 = lg[r2][1];
            float mx = fmaxf(l0, l1);
            float lse = mx + logf(expf(l0 - mx) + expf(l1 - mx));
            float lt = (r2 < 8) ? l1 : l0;
            loss += (lse - lt);
        }
        dout[150002] = loss / 16.f;
        float se = sums[0];
        dout[0] = sums[1] / se;
        dout[1] = sums[2] / se;
    }
}

extern "C" void kernel_launch(void* const* d_in, const int* in_sizes, int n_in,
                              void* d_out, int out_size, void* d_ws, size_t ws_size,
                              hipStream_t stream) {
    const float* h   = (const float*)d_in[0];
    const float* fcW = (const float*)d_in[1];
    const float* fcb = (const float*)d_in[2];
    const float* aaW = (const float*)d_in[3];
    const float* aab = (const float*)d_in[4];
    const float* abW = (const float*)d_in[5];
    const float* abb = (const float*)d_in[6];
    const float* acW = (const float*)d_in[7];
    const float* acb = (const float*)d_in[8];
    const float* clW = (const float*)d_in[9];
    const float* clb = (const float*)d_in[10];
    const float* inW = (const float*)d_in[11];
    const float* inb = (const float*)d_in[12];
    float* out = (float*)d_out;

    char* ws = (char*)d_ws;
    bf16_t* hh      = (bf16_t*)(ws);                       // 51,200,000 B
    bf16_t* permW1  = (bf16_t*)(ws + 51200000);            // 1,048,576 B
    bf16_t* permB2  = (bf16_t*)(ws + 52248576);            // 524,288 B
    float*  sums    = (float*) (ws + 52772864);            // 16 B
    int*    ids     = (int*)   (ws + 52772928);            // 64 B

    float* inst = out + 2;
    float* Araw = out + 2 + 100000;

    k_convert<<<256, 256, 0, stream>>>(fcW, aaW, abW, permW1, permB2);
    k_gemm1<<<782, 512, 0, stream>>>(h, permW1, fcb, hh);
    k_gemm2<<<782, 512, 0, stream>>>(hh, permB2, aab, abb, acW, acb, clW, clb, Araw, inst);
    k_topk<<<2, 512, 0, stream>>>(Araw, ids, sums);
    k_sum<<<128, 256, 0, stream>>>(Araw, inst, ids, sums);
    k_fin<<<1, 256, 0, stream>>>(hh, ids, sums, inW, inb, out);
}

// Round 3
// 547.745 us; speedup vs baseline: 1.3283x; 1.0729x over previous
//
#include <hip/hip_runtime.h>
#include <hip/hip_bf16.h>
#include <math.h>

typedef __bf16 bf16_t;
typedef __bf16 bf16x8 __attribute__((ext_vector_type(8)));
typedef float  f32x4  __attribute__((ext_vector_type(4)));

#define NROWS 50000

typedef const __attribute__((address_space(1))) unsigned int* gp_t;
typedef __attribute__((address_space(3))) unsigned int* lp_t;
__device__ __forceinline__ void cp16(void* l, const void* g) {
    __builtin_amdgcn_global_load_lds((gp_t)g, (lp_t)l, 16, 0, 0);
}

// ---------------- weight permutation ----------------
// permW1[kt 0..31][q 0..3][row 0..511][8]  = fcW[row][kt*32+q*8+i]   (bf16)
// permB2[kt 0..15][q 0..3][row 0..511][8]  = interleaved a/b W rows  (bf16)
__global__ void k_convert(const float* __restrict__ fcW,
                          const float* __restrict__ aW,
                          const float* __restrict__ bW,
                          bf16_t* __restrict__ permW1, bf16_t* __restrict__ permB2) {
    int t = blockIdx.x * 256 + threadIdx.x;   // 65536 total
    {
        int row = t & 511, q = (t >> 9) & 3, kt = t >> 11;
        const float* src = fcW + (long)row * 1024 + kt * 32 + q * 8;
        bf16_t o[8];
        #pragma unroll
        for (int i = 0; i < 8; i++) o[i] = (bf16_t)src[i];
        *(bf16x8*)(permW1 + (long)t * 8) = *(bf16x8*)o;
    }
    if (t < 32768) {
        int row = t & 511, q = (t >> 9) & 3, kt = t >> 11;
        int g = row >> 4, u = g >> 1, j = u * 16 + (row & 15);
        const float* src = ((g & 1) ? bW : aW) + (long)j * 512 + kt * 32 + q * 8;
        bf16_t o[8];
        #pragma unroll
        for (int i = 0; i < 8; i++) o[i] = (bf16_t)src[i];
        *(bf16x8*)(permB2 + (long)t * 8) = *(bf16x8*)o;
    }
}

// ---------------- GEMM1: hh = relu(x @ fc_W^T + fc_b), double-buffered pipeline ----------------
__global__ __launch_bounds__(512, 4) void k_gemm1(
        const float* __restrict__ x, const bf16_t* __restrict__ permW1,
        const float* __restrict__ fcb, bf16_t* __restrict__ hh) {
    // layout: bs0 @0 (32K), bs1 @32768, xs0 @65536 (5120), xs1 @70656 ; epilogue t16 overlays @0
    __shared__ __align__(16) char smem[75776];

    const int tid = threadIdx.x;
    const int w  = tid >> 6;
    const int l  = tid & 63;
    const int q  = l >> 4;
    const int li = l & 15;
    const long row0 = (long)blockIdx.x * 64;

    f32x4 acc[4][4];
    #pragma unroll
    for (int a = 0; a < 4; a++)
        #pragma unroll
        for (int b = 0; b < 4; b++) acc[a][b] = (f32x4)0.0f;

    const int rx = tid >> 3;            // x staging row 0..63
    const int kx = (tid & 7) * 4;       // 4 floats
    const long xrow = row0 + rx;
    const bool xvalid = (xrow < NROWS);
    const float* xp = x + xrow * 1024 + kx;

    // ---- prologue: stage kt=0 into buf 0 ----
    float4 xv = xvalid ? *(const float4*)xp : make_float4(0.f, 0.f, 0.f, 0.f);
    {
        union { bf16_t h[4]; unsigned long long u; } pk;
        pk.h[0] = (bf16_t)xv.x; pk.h[1] = (bf16_t)xv.y;
        pk.h[2] = (bf16_t)xv.z; pk.h[3] = (bf16_t)xv.w;
        *(unsigned long long*)(smem + 65536 + (rx * 40 + kx) * 2) = pk.u;
    }
    xv = xvalid ? *(const float4*)(xp + 32) : make_float4(0.f, 0.f, 0.f, 0.f);
    {
        const bf16_t* gw = permW1 + (long)tid * 8;    // kt = 0
        char* dst = smem + tid * 16;
        #pragma unroll
        for (int j = 0; j < 4; j++) cp16(dst + j * 8192, gw + j * 4096);
    }
    __syncthreads();

    for (int kt = 0; kt < 32; kt++) {
        const int cur = kt & 1;
        const int nxt = cur ^ 1;
        if (kt < 31) {
            // stage B tile kt+1 into bs[nxt]
            const bf16_t* gw = permW1 + ((long)(kt + 1) * 2048 + tid) * 8;
            char* dst = smem + nxt * 32768 + tid * 16;
            #pragma unroll
            for (int j = 0; j < 4; j++) cp16(dst + j * 8192, gw + j * 4096);
            // stage x tile kt+1 into xs[nxt] from prefetched regs
            union { bf16_t h[4]; unsigned long long u; } pk;
            pk.h[0] = (bf16_t)xv.x; pk.h[1] = (bf16_t)xv.y;
            pk.h[2] = (bf16_t)xv.z; pk.h[3] = (bf16_t)xv.w;
            *(unsigned long long*)(smem + 65536 + nxt * 5120 + (rx * 40 + kx) * 2) = pk.u;
            // prefetch x tile kt+2
            int kn = (kt < 30 ? kt + 2 : 31) * 32;
            xv = xvalid ? *(const float4*)(xp + kn) : make_float4(0.f, 0.f, 0.f, 0.f);
        }
        // ---- MFMA on buf cur ----
        const bf16_t* bsb = (const bf16_t*)(smem + cur * 32768);
        const bf16_t* xsb = (const bf16_t*)(smem + 65536 + cur * 5120);
        bf16x8 bfr[4];
        #pragma unroll
        for (int tn = 0; tn < 4; tn++)
            bfr[tn] = *(const bf16x8*)(bsb + q * 4096 + (w * 64 + tn * 16 + li) * 8);
        #pragma unroll
        for (int tm = 0; tm < 4; tm++) {
            bf16x8 af = *(const bf16x8*)(xsb + (tm * 16 + li) * 40 + q * 8);
            #pragma unroll
            for (int tn = 0; tn < 4; tn++)
                acc[tm][tn] = __builtin_amdgcn_mfma_f32_16x16x32_bf16(af, bfr[tn], acc[tm][tn], 0, 0, 0);
        }
        __syncthreads();
    }

    // ---- epilogue: bias+relu, LDS transpose, coalesced bf16x16 stores ----
    bf16_t* t16 = (bf16_t*)smem;     // [16][520]
    float bias[4];
    #pragma unroll
    for (int tn = 0; tn < 4; tn++) bias[tn] = fcb[w * 64 + tn * 16 + li];

    const int rr = tid >> 5;          // 0..15
    const int cc = tid & 31;          // 32B chunk
    #pragma unroll
    for (int tm = 0; tm < 4; tm++) {
        #pragma unroll
        for (int tn = 0; tn < 4; tn++) {
            int col = w * 64 + tn * 16 + li;
            #pragma unroll
            for (int r = 0; r < 4; r++) {
                float v = acc[tm][tn][r] + bias[tn];
                v = v > 0.f ? v : 0.f;
                t16[(q * 4 + r) * 520 + col] = (bf16_t)v;
            }
        }
        __syncthreads();
        long row = row0 + tm * 16 + rr;
        if (row < NROWS) {
            bf16x8 v0 = *(const bf16x8*)&t16[rr * 520 + cc * 16];
            bf16x8 v1 = *(const bf16x8*)&t16[rr * 520 + cc * 16 + 8];
            *(bf16x8*)&hh[row * 512 + cc * 16] = v0;
            *(bf16x8*)&hh[row * 512 + cc * 16 + 8] = v1;
        }
        __syncthreads();
    }
}

// ---------------- GEMM2: fused att(a,b,c)->Araw + cls -> inst, double-buffered ----------------
__global__ __launch_bounds__(512, 4) void k_gemm2(
        const bf16_t* __restrict__ hh, const bf16_t* __restrict__ permB2,
        const float* __restrict__ aab, const float* __restrict__ abb,
        const float* __restrict__ acW, const float* __restrict__ acb,
        const float* __restrict__ clsW, const float* __restrict__ clsb,
        float* __restrict__ Araw, float* __restrict__ inst) {
    // layout: as0 @0 (4K), as1 @4096, bs0 @8192 (32K), bs1 @40960 ; total 73728
    // epilogue overlay: apart @0 (2304), cls_part @4096 (4096)
    __shared__ __align__(16) char smem[73728];
    __shared__ bf16_t cls_lds[1024];          // [2][512]

    const int tid = threadIdx.x;
    const int w  = tid >> 6;
    const int l  = tid & 63;
    const int q  = l >> 4;
    const int li = l & 15;
    const long row0 = (long)blockIdx.x * 64;

    // stage cls weights once (bf16)
    if (tid < 128) {
        int c = tid >> 6, k8 = (tid & 63) * 8;
        #pragma unroll
        for (int i = 0; i < 8; i++)
            cls_lds[c * 512 + k8 + i] = (bf16_t)clsW[c * 512 + k8 + i];
    }

    f32x4 acc[4][4];
    #pragma unroll
    for (int a = 0; a < 4; a++)
        #pragma unroll
        for (int b = 0; b < 4; b++) acc[a][b] = (f32x4)0.0f;
    float cls0[4] = {0.f,0.f,0.f,0.f}, cls1[4] = {0.f,0.f,0.f,0.f};

    // ---- prologue: stage kt=0 into buf 0 ----
    {
        const bf16_t* gb = permB2 + (long)tid * 8;
        char* dst = smem + 8192 + tid * 16;
        #pragma unroll
        for (int j = 0; j < 4; j++) cp16(dst + j * 8192, gb + j * 4096);
        if (tid < 256) {
            const bf16_t* ga = hh + (row0 + (tid >> 2)) * 512 + (tid & 3) * 8;
            cp16(smem + tid * 16, ga);
        }
    }
    __syncthreads();

    for (int kt = 0; kt < 16; kt++) {
        const int cur = kt & 1;
        const int nxt = cur ^ 1;
        if (kt < 15) {
            const bf16_t* gb = permB2 + ((long)(kt + 1) * 2048 + tid) * 8;
            char* dst = smem + 8192 + nxt * 32768 + tid * 16;
            #pragma unroll
            for (int j = 0; j < 4; j++) cp16(dst + j * 8192, gb + j * 4096);
            if (tid < 256) {
                const bf16_t* ga = hh + (row0 + (tid >> 2)) * 512 + (kt + 1) * 32 + (tid & 3) * 8;
                cp16(smem + nxt * 4096 + tid * 16, ga);
            }
        }
        const bf16_t* asb = (const bf16_t*)(smem + cur * 4096);
        const bf16_t* bsb = (const bf16_t*)(smem + 8192 + cur * 32768);
        bf16x8 bfr[4];
        #pragma unroll
        for (int tn = 0; tn < 4; tn++)
            bfr[tn] = *(const bf16x8*)(bsb + q * 4096 + (w * 64 + tn * 16 + li) * 8);
        const bool mycls = ((kt >> 1) == w);
        bf16x8 w0, w1;
        if (mycls) {
            w0 = *(const bf16x8*)&cls_lds[kt * 32 + q * 8];
            w1 = *(const bf16x8*)&cls_lds[512 + kt * 32 + q * 8];
        }
        #pragma unroll
        for (int tm = 0; tm < 4; tm++) {
            bf16x8 af = *(const bf16x8*)(asb + (tm * 16 + li) * 32 + q * 8);
            #pragma unroll
            for (int tn = 0; tn < 4; tn++)
                acc[tm][tn] = __builtin_amdgcn_mfma_f32_16x16x32_bf16(af, bfr[tn], acc[tm][tn], 0, 0, 0);
            if (mycls) {
                float s0 = 0.f, s1 = 0.f;
                #pragma unroll
                for (int jj = 0; jj < 8; jj++) {
                    float a = (float)af[jj];
                    s0 += a * (float)w0[jj];
                    s1 += a * (float)w1[jj];
                }
                cls0[tm] += s0; cls1[tm] += s1;
            }
        }
        __syncthreads();
    }

    // ---- attention epilogue ----
    float (*apart)[9] = (float (*)[9])smem;              // [64][9]
    float (*cls_part)[64][2] = (float (*)[64][2])(smem + 4096);   // [8][64][2]

    float sum_mr[4][4];
    #pragma unroll
    for (int a = 0; a < 4; a++)
        #pragma unroll
        for (int b = 0; b < 4; b++) sum_mr[a][b] = 0.f;
    #pragma unroll
    for (int p = 0; p < 2; p++) {
        int j = (w * 2 + p) * 16 + li;
        float ab_ = aab[j], bb_ = abb[j], cw = acW[j];
        int tn_a = p * 2, tn_b = p * 2 + 1;
        #pragma unroll
        for (int tm = 0; tm < 4; tm++)
            #pragma unroll
            for (int r = 0; r < 4; r++) {
                float av = tanhf(acc[tm][tn_a][r] + ab_);
                float bv = acc[tm][tn_b][r] + bb_;
                bv = 1.f / (1.f + expf(-bv));
                sum_mr[tm][r] += av * bv * cw;
            }
    }
    #pragma unroll
    for (int tm = 0; tm < 4; tm++)
        #pragma unroll
        for (int r = 0; r < 4; r++) {
            float v = sum_mr[tm][r];
            v += __shfl_xor(v, 1); v += __shfl_xor(v, 2);
            v += __shfl_xor(v, 4); v += __shfl_xor(v, 8);
            if (li == 0) apart[tm * 16 + q * 4 + r][w] = v;
        }
    #pragma unroll
    for (int tm = 0; tm < 4; tm++) {
        cls0[tm] += __shfl_xor(cls0[tm], 16); cls0[tm] += __shfl_xor(cls0[tm], 32);
        cls1[tm] += __shfl_xor(cls1[tm], 16); cls1[tm] += __shfl_xor(cls1[tm], 32);
        if (q == 0) {
            cls_part[w][tm * 16 + li][0] = cls0[tm];
            cls_part[w][tm * 16 + li][1] = cls1[tm];
        }
    }
    __syncthreads();
    if (tid < 64) {
        float s = acb[0];
        #pragma unroll
        for (int ww = 0; ww < 8; ww++) s += apart[tid][ww];
        long row = row0 + tid;
        if (row < NROWS) Araw[row] = s;
    }
    if (tid < 128) {
        int rr = tid >> 1, c = tid & 1;
        float s = clsb[c];
        #pragma unroll
        for (int ww = 0; ww < 8; ww++) s += cls_part[ww][rr][c];
        long row = row0 + rr;
        if (row < NROWS) inst[row * 2 + c] = s;
    }
}

// ---------------- top-8 / bottom-8 (JAX tie-break: lower idx wins), 2 blocks ----------------
__global__ void k_topk(const float* __restrict__ scores, int* __restrict__ ids,
                       float* __restrict__ sums) {
    __shared__ float cv[4096];
    __shared__ int   ci[4096];
    __shared__ float bwv[8]; __shared__ int bwi[8]; __shared__ int bws[8];
    int tid = threadIdx.x;        // 512 threads
    int pass = blockIdx.x;        // 0: top, 1: bottom
    if (pass == 0 && tid == 0) { sums[0] = 0.f; sums[1] = 0.f; sums[2] = 0.f; }
    float sign = (pass == 0) ? 1.f : -1.f;
    float tv[8]; int ti[8];
    #pragma unroll
    for (int k = 0; k < 8; k++) { tv[k] = -1e30f; ti[k] = 0x7fffffff; }
    for (int i = tid; i < NROWS; i += 512) {
        float v = sign * scores[i];
        if (v > tv[7] || (v == tv[7] && i < ti[7])) {
            int k = 7;
            while (k > 0 && (v > tv[k-1] || (v == tv[k-1] && i < ti[k-1]))) {
                tv[k] = tv[k-1]; ti[k] = ti[k-1]; k--;
            }
            tv[k] = v; ti[k] = i;
        }
    }
    for (int k = 0; k < 8; k++) { cv[tid * 8 + k] = tv[k]; ci[tid * 8 + k] = ti[k]; }
    __syncthreads();
    for (int r = 0; r < 8; r++) {
        float bv = -1e30f; int bi = 0x7fffffff, bslot = 0;
        for (int j = 0; j < 8; j++) {
            int s = tid + 512 * j;
            float v = cv[s]; int idx = ci[s];
            if (v > bv || (v == bv && idx < bi)) { bv = v; bi = idx; bslot = s; }
        }
        for (int m = 1; m < 64; m <<= 1) {
            float ov = __shfl_xor(bv, m); int oi = __shfl_xor(bi, m); int os = __shfl_xor(bslot, m);
            if (ov > bv || (ov == bv && oi < bi)) { bv = ov; bi = oi; bslot = os; }
        }
        if ((tid & 63) == 0) { bwv[tid >> 6] = bv; bwi[tid >> 6] = bi; bws[tid >> 6] = bslot; }
        __syncthreads();
        if (tid == 0) {
            float BV = -1e30f; int BI = 0x7fffffff, BS = 0;
            for (int wv = 0; wv < 8; wv++) {
                if (bwv[wv] > BV || (bwv[wv] == BV && bwi[wv] < BI)) { BV = bwv[wv]; BI = bwi[wv]; BS = bws[wv]; }
            }
            ids[pass * 8 + r] = BI;
            cv[BS] = -1e30f; ci[BS] = 0x7fffffff;
        }
        __syncthreads();
    }
}

// ---------------- softmax-weighted sums (max taken from top-1) ----------------
__global__ void k_sum(const float* __restrict__ Araw, const float* __restrict__ inst,
                      const int* __restrict__ ids, float* sums) {
    __shared__ float r0[4], r1[4], r2[4];
    int tid = threadIdx.x;
    float mx = Araw[ids[0]];
    float se = 0.f, s0 = 0.f, s1 = 0.f;
    for (int i = blockIdx.x * 256 + tid; i < NROWS; i += 32768) {
        float e = expf(Araw[i] - mx);
        se += e; s0 += inst[2 * i] * e; s1 += inst[2 * i + 1] * e;
    }
    for (int s = 1; s < 64; s <<= 1) {
        se += __shfl_xor(se, s); s0 += __shfl_xor(s0, s); s1 += __shfl_xor(s1, s);
    }
    if ((tid & 63) == 0) { r0[tid >> 6] = se; r1[tid >> 6] = s0; r2[tid >> 6] = s1; }
    __syncthreads();
    if (tid == 0) {
        atomicAdd(&sums[0], r0[0] + r0[1] + r0[2] + r0[3]);
        atomicAdd(&sums[1], r1[0] + r1[1] + r1[2] + r1[3]);
        atomicAdd(&sums[2], r2[0] + r2[1] + r2[2] + r2[3]);
    }
}

// ---------------- finalize: preds + instance_loss ----------------
__global__ void k_fin(const bf16_t* __restrict__ hh, const int* __restrict__ ids,
                      const float* __restrict__ sums, const float* __restrict__ instW,
                      const float* __restrict__ instb, float* __restrict__ dout) {
    __shared__ float lg[16][2];
    int tid = threadIdx.x;          // 256 threads
    int r  = tid >> 4;              // 16 rows
    int li = tid & 15;
    int id = ids[r];
    const bf16_t* hp = hh + (long)id * 512;
    float p0 = 0.f, p1 = 0.f;
    for (int k = li * 32; k < li * 32 + 32; k++) {
        float h = (float)hp[k];
        p0 += h * instW[k]; p1 += h * instW[512 + k];
    }
    for (int m = 1; m < 16; m <<= 1) { p0 += __shfl_xor(p0, m); p1 += __shfl_xor(p1, m); }
    if (li == 0) { lg[r][0] = p0 + instb[0]; lg[r][1] = p1 + instb[1]; }
    __syncthreads();
    if (tid == 0) {
        float loss = 0.f;
        for (int r2 = 0; r2 < 16; r2++) {
            float l0 = lg[r2][0], l1 = lg[r2][1];
            float mx = fmaxf(l0, l1);
            float lse = mx + logf(expf(l0 - mx) + expf(l1 - mx));
            float lt = (r2 < 8) ? l1 : l0;
            loss += (lse - lt);
        }
        dout[150002] = loss / 16.f;
        float se = sums[0];
        dout[0] = sums[1] / se;
        dout[1] = sums[2] / se;
    }
}

extern "C" void kernel_launch(void* const* d_in, const int* in_sizes, int n_in,
                              void* d_out, int out_size, void* d_ws, size_t ws_size,
                              hipStream_t stream) {
    const float* h   = (const float*)d_in[0];
    const float* fcW = (const float*)d_in[1];
    const float* fcb = (const float*)d_in[2];
    const float* aaW = (const float*)d_in[3];
    const float* aab = (const float*)d_in[4];
    const float* abW = (const float*)d_in[5];
    const float* abb = (const float*)d_in[6];
    const float* acW = (const float*)d_in[7];
    const float* acb = (const float*)d_in[8];
    const float* clW = (const float*)d_in[9];
    const float* clb = (const float*)d_in[10];
    const float* inW = (const float*)d_in[11];
    const float* inb = (const float*)d_in[12];
    float* out = (float*)d_out;

    char* ws = (char*)d_ws;
    bf16_t* hh      = (bf16_t*)(ws);                       // 51,200,000 B
    bf16_t* permW1  = (bf16_t*)(ws + 51200000);            // 1,048,576 B
    bf16_t* permB2  = (bf16_t*)(ws + 52248576);            // 524,288 B
    float*  sums    = (float*) (ws + 52772864);            // 16 B
    int*    ids     = (int*)   (ws + 52772928);            // 64 B

    float* inst = out + 2;
    float* Araw = out + 2 + 100000;

    k_convert<<<256, 256, 0, stream>>>(fcW, aaW, abW, permW1, permB2);
    k_gemm1<<<782, 512, 0, stream>>>(h, permW1, fcb, hh);
    k_gemm2<<<782, 512, 0, stream>>>(hh, permB2, aab, abb, acW, acb, clW, clb, Araw, inst);
    k_topk<<<2, 512, 0, stream>>>(Araw, ids, sums);
    k_sum<<<128, 256, 0, stream>>>(Araw, inst, ids, sums);
    k_fin<<<1, 256, 0, stream>>>(hh, ids, sums, inW, inb, out);
}

// Round 4
// 488.134 us; speedup vs baseline: 1.4905x; 1.1221x over previous
//
#include <hip/hip_runtime.h>
#include <hip/hip_bf16.h>
#include <math.h>

typedef __bf16 bf16_t;
typedef __bf16 bf16x4 __attribute__((ext_vector_type(4)));
typedef __bf16 bf16x8 __attribute__((ext_vector_type(8)));
typedef float  f32x4  __attribute__((ext_vector_type(4)));

#define NROWS 50000

typedef const __attribute__((address_space(1))) unsigned int* gp_t;
typedef __attribute__((address_space(3))) unsigned int* lp_t;
__device__ __forceinline__ void cp16(void* l, const void* g) {
    __builtin_amdgcn_global_load_lds((gp_t)g, (lp_t)l, 16, 0, 0);
}

// ---------------- weight permutation (coalesced reads, scattered 8B writes) ----------------
// permW1[kt 0..31][q 0..3][row 0..511][8] = fcW[row][kt*32+q*8+j]
// permB2[kt 0..15][q 0..3][r 0..511][8]   = interleaved a/b rows
__global__ void k_convert(const float* __restrict__ fcW,
                          const float* __restrict__ aW,
                          const float* __restrict__ bW,
                          bf16_t* __restrict__ permW1, bf16_t* __restrict__ permB2) {
    int t = blockIdx.x * 256 + threadIdx.x;   // 196608 total
    if (t < 131072) {
        float4 v = *(const float4*)(fcW + (long)t * 4);
        int row = t >> 8;
        int k0 = (t & 255) * 4;
        int kt = k0 >> 5, q = (k0 >> 3) & 3, j = k0 & 7;
        bf16_t o[4] = {(bf16_t)v.x, (bf16_t)v.y, (bf16_t)v.z, (bf16_t)v.w};
        *(bf16x4*)(permW1 + kt * 16384 + q * 4096 + row * 8 + j) = *(bf16x4*)o;
    } else {
        int t2 = t - 131072;        // < 65536
        int isB = t2 >> 15;
        int f = t2 & 32767;
        float4 v = *(const float4*)(((isB ? bW : aW)) + (long)f * 4);
        int srow = f >> 7;
        int k0 = (f & 127) * 4;
        int kt = k0 >> 5, q = (k0 >> 3) & 3, j = k0 & 7;
        int r = ((srow >> 4) * 2 + isB) * 16 + (srow & 15);
        bf16_t o[4] = {(bf16_t)v.x, (bf16_t)v.y, (bf16_t)v.z, (bf16_t)v.w};
        *(bf16x4*)(permB2 + kt * 16384 + q * 4096 + r * 8 + j) = *(bf16x4*)o;
    }
}

// ---------------- GEMM1: 128x128 tiles, 4 col-tiles, 4 blocks/CU, dbuf ----------------
__global__ __launch_bounds__(256, 4) void k_gemm1(
        const float* __restrict__ x, const bf16_t* __restrict__ permW1,
        const float* __restrict__ fcb, bf16_t* __restrict__ hh) {
    // A: [buf][kq4][row128][8] bf16 @0 (8192/buf); B: [buf][q4][col128][8] @16384 (8192/buf)
    __shared__ __align__(16) char smem[32768];
    const int tid = threadIdx.x;
    const int w = tid >> 6, l = tid & 63, q = l >> 4, li = l & 15;
    const int wr = w >> 1, wc = w & 1;
    const int b = blockIdx.x;
    const int rtile = (b & 7) | ((b >> 5) << 3);   // all 4 col-tiles of a row-band -> same XCD slot
    const int ctile = (b >> 3) & 3;
    const long row0 = (long)rtile * 128;
    const int col0 = ctile * 128;

    f32x4 acc[4][4];
    #pragma unroll
    for (int a = 0; a < 4; a++)
        #pragma unroll
        for (int c = 0; c < 4; c++) acc[a][c] = (f32x4)0.0f;

    int arow[4], akx[4]; bool avalid[4];
    #pragma unroll
    for (int j = 0; j < 4; j++) {
        int s = j * 256 + tid;
        arow[j] = s >> 3; akx[j] = s & 7;
        avalid[j] = (row0 + arow[j]) < NROWS;
    }
    const float* xbase = x + row0 * 1024;

    float4 xv[4];
    // ---- prologue: A(kt0)+B(kt0) -> buf0, prefetch xv(kt1) ----
    #pragma unroll
    for (int j = 0; j < 4; j++)
        xv[j] = avalid[j] ? *(const float4*)(xbase + arow[j] * 1024 + akx[j] * 4)
                          : make_float4(0.f, 0.f, 0.f, 0.f);
    #pragma unroll
    for (int j = 0; j < 4; j++) {
        bf16_t o[4] = {(bf16_t)xv[j].x, (bf16_t)xv[j].y, (bf16_t)xv[j].z, (bf16_t)xv[j].w};
        *(bf16x4*)(smem + (akx[j] >> 1) * 2048 + arow[j] * 16 + (akx[j] & 1) * 8) = *(bf16x4*)o;
    }
    #pragma unroll
    for (int s2 = 0; s2 < 2; s2++) {
        int s = tid + s2 * 256;
        cp16(smem + 16384 + s * 16, permW1 + (s >> 7) * 4096 + (col0 + (s & 127)) * 8);
    }
    #pragma unroll
    for (int j = 0; j < 4; j++)
        xv[j] = avalid[j] ? *(const float4*)(xbase + arow[j] * 1024 + 32 + akx[j] * 4)
                          : make_float4(0.f, 0.f, 0.f, 0.f);
    __syncthreads();

    for (int kt = 0; kt < 32; kt++) {
        const int cur = kt & 1, nxt = cur ^ 1;
        if (kt < 31) {
            const bf16_t* gsrc = permW1 + (long)(kt + 1) * 16384;
            #pragma unroll
            for (int s2 = 0; s2 < 2; s2++) {
                int s = tid + s2 * 256;
                cp16(smem + 16384 + nxt * 8192 + s * 16, gsrc + (s >> 7) * 4096 + (col0 + (s & 127)) * 8);
            }
            #pragma unroll
            for (int j = 0; j < 4; j++) {
                bf16_t o[4] = {(bf16_t)xv[j].x, (bf16_t)xv[j].y, (bf16_t)xv[j].z, (bf16_t)xv[j].w};
                *(bf16x4*)(smem + nxt * 8192 + (akx[j] >> 1) * 2048 + arow[j] * 16 + (akx[j] & 1) * 8) = *(bf16x4*)o;
            }
            int kn = (kt < 30 ? kt + 2 : 31) * 32;
            #pragma unroll
            for (int j = 0; j < 4; j++)
                xv[j] = avalid[j] ? *(const float4*)(xbase + arow[j] * 1024 + kn + akx[j] * 4)
                                  : make_float4(0.f, 0.f, 0.f, 0.f);
        }
        const bf16_t* Ab = (const bf16_t*)(smem + cur * 8192);
        const bf16_t* Bb = (const bf16_t*)(smem + 16384 + cur * 8192);
        bf16x8 afr[4], bfr[4];
        #pragma unroll
        for (int tn = 0; tn < 4; tn++)
            bfr[tn] = *(const bf16x8*)(Bb + q * 1024 + (wc * 64 + tn * 16 + li) * 8);
        #pragma unroll
        for (int tm = 0; tm < 4; tm++)
            afr[tm] = *(const bf16x8*)(Ab + q * 1024 + (wr * 64 + tm * 16 + li) * 8);
        #pragma unroll
        for (int tm = 0; tm < 4; tm++)
            #pragma unroll
            for (int tn = 0; tn < 4; tn++)
                acc[tm][tn] = __builtin_amdgcn_mfma_f32_16x16x32_bf16(afr[tm], bfr[tn], acc[tm][tn], 0, 0, 0);
        __syncthreads();
    }

    // ---- epilogue: bias+relu, LDS transpose [32][136], coalesced stores ----
    bf16_t* t16 = (bf16_t*)smem;
    float bias[4];
    #pragma unroll
    for (int tn = 0; tn < 4; tn++) bias[tn] = fcb[col0 + wc * 64 + tn * 16 + li];
    const int rr = tid >> 3, cc = tid & 7;
    #pragma unroll
    for (int tm = 0; tm < 4; tm++) {
        #pragma unroll
        for (int tn = 0; tn < 4; tn++)
            #pragma unroll
            for (int r = 0; r < 4; r++) {
                float v = acc[tm][tn][r] + bias[tn];
                v = v > 0.f ? v : 0.f;
                t16[(wr * 16 + q * 4 + r) * 136 + wc * 64 + tn * 16 + li] = (bf16_t)v;
            }
        __syncthreads();
        long grow = row0 + ((rr >> 4) * 64) + tm * 16 + (rr & 15);
        if (grow < NROWS) {
            bf16x8 v0 = *(const bf16x8*)&t16[rr * 136 + cc * 16];
            bf16x8 v1 = *(const bf16x8*)&t16[rr * 136 + cc * 16 + 8];
            *(bf16x8*)&hh[grow * 512 + col0 + cc * 16] = v0;
            *(bf16x8*)&hh[grow * 512 + col0 + cc * 16 + 8] = v1;
        }
        __syncthreads();
    }
}

// ---------------- GEMM2: fused att(a,b,c)->Araw + cls -> inst, dbuf, 2 blocks/CU ----------------
__global__ __launch_bounds__(512, 4) void k_gemm2(
        const bf16_t* __restrict__ hh, const bf16_t* __restrict__ permB2,
        const float* __restrict__ aab, const float* __restrict__ abb,
        const float* __restrict__ acW, const float* __restrict__ acb,
        const float* __restrict__ clsW, const float* __restrict__ clsb,
        float* __restrict__ Araw, float* __restrict__ inst) {
    // as0 @0 (4K), as1 @4096, bs0 @8192 (32K), bs1 @40960, cls_lds @73728 (2048) -> 75776 total
    // epilogue overlays: apart @0 (2304), cls_part @4096 (4096)
    __shared__ __align__(16) char smem[75776];
    bf16_t* cls_lds = (bf16_t*)(smem + 73728);

    const int tid = threadIdx.x;
    const int w = tid >> 6, l = tid & 63, q = l >> 4, li = l & 15;
    const long row0 = (long)blockIdx.x * 64;

    if (tid < 128) {
        int c = tid >> 6, k8 = (tid & 63) * 8;
        #pragma unroll
        for (int i = 0; i < 8; i++)
            cls_lds[c * 512 + k8 + i] = (bf16_t)clsW[c * 512 + k8 + i];
    }

    f32x4 acc[4][4];
    #pragma unroll
    for (int a = 0; a < 4; a++)
        #pragma unroll
        for (int c = 0; c < 4; c++) acc[a][c] = (f32x4)0.0f;
    float cls0[4] = {0.f,0.f,0.f,0.f}, cls1[4] = {0.f,0.f,0.f,0.f};

    {
        const bf16_t* gb = permB2 + (long)tid * 8;
        char* dst = smem + 8192 + tid * 16;
        #pragma unroll
        for (int j = 0; j < 4; j++) cp16(dst + j * 8192, gb + j * 4096);
        if (tid < 256) {
            const bf16_t* ga = hh + (row0 + (tid >> 2)) * 512 + (tid & 3) * 8;
            cp16(smem + tid * 16, ga);
        }
    }
    __syncthreads();

    for (int kt = 0; kt < 16; kt++) {
        const int cur = kt & 1, nxt = cur ^ 1;
        if (kt < 15) {
            const bf16_t* gb = permB2 + ((long)(kt + 1) * 2048 + tid) * 8;
            char* dst = smem + 8192 + nxt * 32768 + tid * 16;
            #pragma unroll
            for (int j = 0; j < 4; j++) cp16(dst + j * 8192, gb + j * 4096);
            if (tid < 256) {
                const bf16_t* ga = hh + (row0 + (tid >> 2)) * 512 + (kt + 1) * 32 + (tid & 3) * 8;
                cp16(smem + nxt * 4096 + tid * 16, ga);
            }
        }
        const bf16_t* asb = (const bf16_t*)(smem + cur * 4096);
        const bf16_t* bsb = (const bf16_t*)(smem + 8192 + cur * 32768);
        bf16x8 bfr[4];
        #pragma unroll
        for (int tn = 0; tn < 4; tn++)
            bfr[tn] = *(const bf16x8*)(bsb + q * 4096 + (w * 64 + tn * 16 + li) * 8);
        const bool mycls = ((kt >> 1) == w);
        bf16x8 w0, w1;
        if (mycls) {
            w0 = *(const bf16x8*)&cls_lds[kt * 32 + q * 8];
            w1 = *(const bf16x8*)&cls_lds[512 + kt * 32 + q * 8];
        }
        #pragma unroll
        for (int tm = 0; tm < 4; tm++) {
            bf16x8 af = *(const bf16x8*)(asb + (tm * 16 + li) * 32 + q * 8);
            #pragma unroll
            for (int tn = 0; tn < 4; tn++)
                acc[tm][tn] = __builtin_amdgcn_mfma_f32_16x16x32_bf16(af, bfr[tn], acc[tm][tn], 0, 0, 0);
            if (mycls) {
                float s0 = 0.f, s1 = 0.f;
                #pragma unroll
                for (int jj = 0; jj < 8; jj++) {
                    float a = (float)af[jj];
                    s0 += a * (float)w0[jj];
                    s1 += a * (float)w1[jj];
                }
                cls0[tm] += s0; cls1[tm] += s1;
            }
        }
        __syncthreads();
    }

    float (*apart)[9] = (float (*)[9])smem;                        // [64][9]
    float (*cls_part)[64][2] = (float (*)[64][2])(smem + 4096);    // [8][64][2]

    float sum_mr[4][4];
    #pragma unroll
    for (int a = 0; a < 4; a++)
        #pragma unroll
        for (int c = 0; c < 4; c++) sum_mr[a][c] = 0.f;
    #pragma unroll
    for (int p = 0; p < 2; p++) {
        int j = (w * 2 + p) * 16 + li;
        float ab_ = aab[j], bb_ = abb[j], cw = acW[j];
        int tn_a = p * 2, tn_b = p * 2 + 1;
        #pragma unroll
        for (int tm = 0; tm < 4; tm++)
            #pragma unroll
            for (int r = 0; r < 4; r++) {
                float av = tanhf(acc[tm][tn_a][r] + ab_);
                float bv = acc[tm][tn_b][r] + bb_;
                bv = 1.f / (1.f + expf(-bv));
                sum_mr[tm][r] += av * bv * cw;
            }
    }
    #pragma unroll
    for (int tm = 0; tm < 4; tm++)
        #pragma unroll
        for (int r = 0; r < 4; r++) {
            float v = sum_mr[tm][r];
            v += __shfl_xor(v, 1); v += __shfl_xor(v, 2);
            v += __shfl_xor(v, 4); v += __shfl_xor(v, 8);
            if (li == 0) apart[tm * 16 + q * 4 + r][w] = v;
        }
    #pragma unroll
    for (int tm = 0; tm < 4; tm++) {
        cls0[tm] += __shfl_xor(cls0[tm], 16); cls0[tm] += __shfl_xor(cls0[tm], 32);
        cls1[tm] += __shfl_xor(cls1[tm], 16); cls1[tm] += __shfl_xor(cls1[tm], 32);
        if (q == 0) {
            cls_part[w][tm * 16 + li][0] = cls0[tm];
            cls_part[w][tm * 16 + li][1] = cls1[tm];
        }
    }
    __syncthreads();
    if (tid < 64) {
        float s = acb[0];
        #pragma unroll
        for (int ww = 0; ww < 8; ww++) s += apart[tid][ww];
        long row = row0 + tid;
        if (row < NROWS) Araw[row] = s;
    }
    if (tid < 128) {
        int rr = tid >> 1, c = tid & 1;
        float s = clsb[c];
        #pragma unroll
        for (int ww = 0; ww < 8; ww++) s += cls_part[ww][rr][c];
        long row = row0 + rr;
        if (row < NROWS) inst[row * 2 + c] = s;
    }
}

// ---------------- top-8/bottom-8 partials: 8 blocks, JAX tie-break ----------------
__global__ void k_topk_part(const float* __restrict__ scores,
                            float* __restrict__ candV, int* __restrict__ candI,
                            float* __restrict__ sums) {
    __shared__ float cv[4096];
    __shared__ int   ci[4096];
    __shared__ float bwv[8]; __shared__ int bwi[8]; __shared__ int bws[8];
    int tid = threadIdx.x;        // 512
    int p = blockIdx.x;           // 0..7
    if (p == 0 && tid == 0) { sums[0] = 0.f; sums[1] = 0.f; sums[2] = 0.f; }
    int lo = p * 6250, hi = lo + 6250;
    for (int pass = 0; pass < 2; pass++) {
        float sign = (pass == 0) ? 1.f : -1.f;
        float tv[8]; int ti[8];
        #pragma unroll
        for (int k = 0; k < 8; k++) { tv[k] = -1e30f; ti[k] = 0x7fffffff; }
        for (int i = lo + tid; i < hi; i += 512) {
            float v = sign * scores[i];
            if (v > tv[7] || (v == tv[7] && i < ti[7])) {
                int k = 7;
                while (k > 0 && (v > tv[k-1] || (v == tv[k-1] && i < ti[k-1]))) {
                    tv[k] = tv[k-1]; ti[k] = ti[k-1]; k--;
                }
                tv[k] = v; ti[k] = i;
            }
        }
        for (int k = 0; k < 8; k++) { cv[tid * 8 + k] = tv[k]; ci[tid * 8 + k] = ti[k]; }
        __syncthreads();
        for (int r = 0; r < 8; r++) {
            float bv = -1e30f; int bi = 0x7fffffff, bslot = 0;
            for (int j = 0; j < 8; j++) {
                int s = tid + 512 * j;
                float v = cv[s]; int idx = ci[s];
                if (v > bv || (v == bv && idx < bi)) { bv = v; bi = idx; bslot = s; }
            }
            for (int m = 1; m < 64; m <<= 1) {
                float ov = __shfl_xor(bv, m); int oi = __shfl_xor(bi, m); int os = __shfl_xor(bslot, m);
                if (ov > bv || (ov == bv && oi < bi)) { bv = ov; bi = oi; bslot = os; }
            }
            if ((tid & 63) == 0) { bwv[tid >> 6] = bv; bwi[tid >> 6] = bi; bws[tid >> 6] = bslot; }
            __syncthreads();
            if (tid == 0) {
                float BV = -1e30f; int BI = 0x7fffffff, BS = 0;
                for (int wv = 0; wv < 8; wv++) {
                    if (bwv[wv] > BV || (bwv[wv] == BV && bwi[wv] < BI)) { BV = bwv[wv]; BI = bwi[wv]; BS = bws[wv]; }
                }
                candV[pass * 64 + p * 8 + r] = BV;
                candI[pass * 64 + p * 8 + r] = BI;
                cv[BS] = -1e30f; ci[BS] = 0x7fffffff;
            }
            __syncthreads();
        }
        __syncthreads();
    }
}

// ---------------- softmax-weighted sums (max = best block top-1) ----------------
__global__ void k_sum(const float* __restrict__ Araw, const float* __restrict__ inst,
                      const float* __restrict__ candV, float* sums) {
    __shared__ float r0[4], r1[4], r2[4];
    int tid = threadIdx.x;
    float mx = -1e30f;
    #pragma unroll
    for (int p = 0; p < 8; p++) mx = fmaxf(mx, candV[p * 8]);
    float se = 0.f, s0 = 0.f, s1 = 0.f;
    for (int i = blockIdx.x * 256 + tid; i < NROWS; i += 32768) {
        float e = expf(Araw[i] - mx);
        se += e; s0 += inst[2 * i] * e; s1 += inst[2 * i + 1] * e;
    }
    for (int s = 1; s < 64; s <<= 1) {
        se += __shfl_xor(se, s); s0 += __shfl_xor(s0, s); s1 += __shfl_xor(s1, s);
    }
    if ((tid & 63) == 0) { r0[tid >> 6] = se; r1[tid >> 6] = s0; r2[tid >> 6] = s1; }
    __syncthreads();
    if (tid == 0) {
        atomicAdd(&sums[0], r0[0] + r0[1] + r0[2] + r0[3]);
        atomicAdd(&sums[1], r1[0] + r1[1] + r1[2] + r1[3]);
        atomicAdd(&sums[2], r2[0] + r2[1] + r2[2] + r2[3]);
    }
}

// ---------------- finalize: merge candidates, preds + instance_loss ----------------
__global__ void k_fin(const bf16_t* __restrict__ hh,
                      const float* __restrict__ candV, const int* __restrict__ candI,
                      const float* __restrict__ sums, const float* __restrict__ instW,
                      const float* __restrict__ instb, float* __restrict__ dout) {
    __shared__ int mid[16];
    __shared__ float lg[16][2];
    int tid = threadIdx.x;          // 256
    int wv = tid >> 6, l = tid & 63;
    if (wv < 2) {
        float v = candV[wv * 64 + l];
        int idx = candI[wv * 64 + l];
        for (int r = 0; r < 8; r++) {
            float bv = v; int bi = idx; int bs = l;
            for (int m = 1; m < 64; m <<= 1) {
                float ov = __shfl_xor(bv, m); int oi = __shfl_xor(bi, m); int os = __shfl_xor(bs, m);
                if (ov > bv || (ov == bv && oi < bi)) { bv = ov; bi = oi; bs = os; }
            }
            if (l == 0) mid[wv * 8 + r] = bi;
            if (l == bs) v = -1e30f;
        }
    }
    __syncthreads();
    int r = tid >> 4, li = tid & 15;
    int id = mid[r];
    const bf16_t* hp = hh + (long)id * 512;
    float p0 = 0.f, p1 = 0.f;
    for (int k = li * 32; k < li * 32 + 32; k++) {
        float h = (float)hp[k];
        p0 += h * instW[k]; p1 += h * instW[512 + k];
    }
    for (int m = 1; m < 16; m <<= 1) { p0 += __shfl_xor(p0, m); p1 += __shfl_xor(p1, m); }
    if (li == 0) { lg[r][0] = p0 + instb[0]; lg[r][1] = p1 + instb[1]; }
    __syncthreads();
    if (tid == 0) {
        float loss = 0.f;
        for (int r2 = 0; r2 < 16; r2++) {
            float l0 = lg[r2][0], l1 = lg[r2][1];
            float mx = fmaxf(l0, l1);
            float lse = mx + logf(expf(l0 - mx) + expf(l1 - mx));
            float lt = (r2 < 8) ? l1 : l0;
            loss += (lse - lt);
        }
        dout[150002] = loss / 16.f;
        float se = sums[0];
        dout[0] = sums[1] / se;
        dout[1] = sums[2] / se;
    }
}

extern "C" void kernel_launch(void* const* d_in, const int* in_sizes, int n_in,
                              void* d_out, int out_size, void* d_ws, size_t ws_size,
                              hipStream_t stream) {
    const float* h   = (const float*)d_in[0];
    const float* fcW = (const float*)d_in[1];
    const float* fcb = (const float*)d_in[2];
    const float* aaW = (const float*)d_in[3];
    const float* aab = (const float*)d_in[4];
    const float* abW = (const float*)d_in[5];
    const float* abb = (const float*)d_in[6];
    const float* acW = (const float*)d_in[7];
    const float* acb = (const float*)d_in[8];
    const float* clW = (const float*)d_in[9];
    const float* clb = (const float*)d_in[10];
    const float* inW = (const float*)d_in[11];
    const float* inb = (const float*)d_in[12];
    float* out = (float*)d_out;

    char* ws = (char*)d_ws;
    bf16_t* hh      = (bf16_t*)(ws);                       // 51,200,000 B
    bf16_t* permW1  = (bf16_t*)(ws + 51200000);            // 1,048,576 B
    bf16_t* permB2  = (bf16_t*)(ws + 52248576);            // 524,288 B
    float*  candV   = (float*) (ws + 52772864);            // 512 B
    int*    candI   = (int*)   (ws + 52773888);            // 512 B
    float*  sums    = (float*) (ws + 52774912);            // 16 B

    float* inst = out + 2;
    float* Araw = out + 2 + 100000;

    k_convert<<<768, 256, 0, stream>>>(fcW, aaW, abW, permW1, permB2);
    k_gemm1<<<1568, 256, 0, stream>>>(h, permW1, fcb, hh);
    k_gemm2<<<782, 512, 0, stream>>>(hh, permB2, aab, abb, acW, acb, clW, clb, Araw, inst);
    k_topk_part<<<8, 512, 0, stream>>>(Araw, candV, candI, sums);
    k_sum<<<128, 256, 0, stream>>>(Araw, inst, candV, sums);
    k_fin<<<1, 256, 0, stream>>>(hh, candV, candI, sums, inW, inb, out);
}

// Round 5
// 484.622 us; speedup vs baseline: 1.5013x; 1.0072x over previous
//
#include <hip/hip_runtime.h>
#include <hip/hip_bf16.h>
#include <math.h>

typedef __bf16 bf16_t;
typedef __bf16 bf16x4 __attribute__((ext_vector_type(4)));
typedef __bf16 bf16x8 __attribute__((ext_vector_type(8)));
typedef float  f32x4  __attribute__((ext_vector_type(4)));

#define NROWS 50000

typedef const __attribute__((address_space(1))) unsigned int* gp_t;
typedef __attribute__((address_space(3))) unsigned int* lp_t;
__device__ __forceinline__ void cp16(void* l, const void* g) {
    __builtin_amdgcn_global_load_lds((gp_t)g, (lp_t)l, 16, 0, 0);
}

// ---------------- weight permutation (coalesced reads, scattered 8B writes) ----------------
// permW1[kt 0..31][q 0..3][row 0..511][8] = fcW[row][kt*32+q*8+j]
// permB2[kt 0..15][q 0..3][r 0..511][8]   = interleaved a/b rows
__global__ void k_convert(const float* __restrict__ fcW,
                          const float* __restrict__ aW,
                          const float* __restrict__ bW,
                          const float* __restrict__ clsW,
                          bf16_t* __restrict__ permW1, bf16_t* __restrict__ permB2,
                          bf16_t* __restrict__ clsWb) {
    int t = blockIdx.x * 256 + threadIdx.x;
    if (t < 131072) {
        float4 v = *(const float4*)(fcW + (long)t * 4);
        int row = t >> 8;
        int k0 = (t & 255) * 4;
        int kt = k0 >> 5, q = (k0 >> 3) & 3, j = k0 & 7;
        bf16_t o[4] = {(bf16_t)v.x, (bf16_t)v.y, (bf16_t)v.z, (bf16_t)v.w};
        *(bf16x4*)(permW1 + kt * 16384 + q * 4096 + row * 8 + j) = *(bf16x4*)o;
    } else if (t < 196608) {
        int t2 = t - 131072;
        int isB = t2 >> 15;
        int f = t2 & 32767;
        float4 v = *(const float4*)(((isB ? bW : aW)) + (long)f * 4);
        int srow = f >> 7;
        int k0 = (f & 127) * 4;
        int kt = k0 >> 5, q = (k0 >> 3) & 3, j = k0 & 7;
        int r = ((srow >> 4) * 2 + isB) * 16 + (srow & 15);
        bf16_t o[4] = {(bf16_t)v.x, (bf16_t)v.y, (bf16_t)v.z, (bf16_t)v.w};
        *(bf16x4*)(permB2 + kt * 16384 + q * 4096 + r * 8 + j) = *(bf16x4*)o;
    } else if (t < 197632) {
        int i = t - 196608;     // 0..1023
        clsWb[i] = (bf16_t)clsW[i];
    }
}

// ---------------- GEMM1: 128x128 tiles, 4 col-tiles, dbuf (unchanged from R4) ----------------
__global__ __launch_bounds__(256, 4) void k_gemm1(
        const float* __restrict__ x, const bf16_t* __restrict__ permW1,
        const float* __restrict__ fcb, bf16_t* __restrict__ hh) {
    __shared__ __align__(16) char smem[32768];
    const int tid = threadIdx.x;
    const int w = tid >> 6, l = tid & 63, q = l >> 4, li = l & 15;
    const int wr = w >> 1, wc = w & 1;
    const int b = blockIdx.x;
    const int rtile = (b & 7) | ((b >> 5) << 3);
    const int ctile = (b >> 3) & 3;
    const long row0 = (long)rtile * 128;
    const int col0 = ctile * 128;

    f32x4 acc[4][4];
    #pragma unroll
    for (int a = 0; a < 4; a++)
        #pragma unroll
        for (int c = 0; c < 4; c++) acc[a][c] = (f32x4)0.0f;

    int arow[4], akx[4]; bool avalid[4];
    #pragma unroll
    for (int j = 0; j < 4; j++) {
        int s = j * 256 + tid;
        arow[j] = s >> 3; akx[j] = s & 7;
        avalid[j] = (row0 + arow[j]) < NROWS;
    }
    const float* xbase = x + row0 * 1024;

    float4 xv[4];
    #pragma unroll
    for (int j = 0; j < 4; j++)
        xv[j] = avalid[j] ? *(const float4*)(xbase + arow[j] * 1024 + akx[j] * 4)
                          : make_float4(0.f, 0.f, 0.f, 0.f);
    #pragma unroll
    for (int j = 0; j < 4; j++) {
        bf16_t o[4] = {(bf16_t)xv[j].x, (bf16_t)xv[j].y, (bf16_t)xv[j].z, (bf16_t)xv[j].w};
        *(bf16x4*)(smem + (akx[j] >> 1) * 2048 + arow[j] * 16 + (akx[j] & 1) * 8) = *(bf16x4*)o;
    }
    #pragma unroll
    for (int s2 = 0; s2 < 2; s2++) {
        int s = tid + s2 * 256;
        cp16(smem + 16384 + s * 16, permW1 + (s >> 7) * 4096 + (col0 + (s & 127)) * 8);
    }
    #pragma unroll
    for (int j = 0; j < 4; j++)
        xv[j] = avalid[j] ? *(const float4*)(xbase + arow[j] * 1024 + 32 + akx[j] * 4)
                          : make_float4(0.f, 0.f, 0.f, 0.f);
    __syncthreads();

    for (int kt = 0; kt < 32; kt++) {
        const int cur = kt & 1, nxt = cur ^ 1;
        if (kt < 31) {
            const bf16_t* gsrc = permW1 + (long)(kt + 1) * 16384;
            #pragma unroll
            for (int s2 = 0; s2 < 2; s2++) {
                int s = tid + s2 * 256;
                cp16(smem + 16384 + nxt * 8192 + s * 16, gsrc + (s >> 7) * 4096 + (col0 + (s & 127)) * 8);
            }
            #pragma unroll
            for (int j = 0; j < 4; j++) {
                bf16_t o[4] = {(bf16_t)xv[j].x, (bf16_t)xv[j].y, (bf16_t)xv[j].z, (bf16_t)xv[j].w};
                *(bf16x4*)(smem + nxt * 8192 + (akx[j] >> 1) * 2048 + arow[j] * 16 + (akx[j] & 1) * 8) = *(bf16x4*)o;
            }
            int kn = (kt < 30 ? kt + 2 : 31) * 32;
            #pragma unroll
            for (int j = 0; j < 4; j++)
                xv[j] = avalid[j] ? *(const float4*)(xbase + arow[j] * 1024 + kn + akx[j] * 4)
                                  : make_float4(0.f, 0.f, 0.f, 0.f);
        }
        const bf16_t* Ab = (const bf16_t*)(smem + cur * 8192);
        const bf16_t* Bb = (const bf16_t*)(smem + 16384 + cur * 8192);
        bf16x8 afr[4], bfr[4];
        #pragma unroll
        for (int tn = 0; tn < 4; tn++)
            bfr[tn] = *(const bf16x8*)(Bb + q * 1024 + (wc * 64 + tn * 16 + li) * 8);
        #pragma unroll
        for (int tm = 0; tm < 4; tm++)
            afr[tm] = *(const bf16x8*)(Ab + q * 1024 + (wr * 64 + tm * 16 + li) * 8);
        #pragma unroll
        for (int tm = 0; tm < 4; tm++)
            #pragma unroll
            for (int tn = 0; tn < 4; tn++)
                acc[tm][tn] = __builtin_amdgcn_mfma_f32_16x16x32_bf16(afr[tm], bfr[tn], acc[tm][tn], 0, 0, 0);
        __syncthreads();
    }

    bf16_t* t16 = (bf16_t*)smem;
    float bias[4];
    #pragma unroll
    for (int tn = 0; tn < 4; tn++) bias[tn] = fcb[col0 + wc * 64 + tn * 16 + li];
    const int rr = tid >> 3, cc = tid & 7;
    #pragma unroll
    for (int tm = 0; tm < 4; tm++) {
        #pragma unroll
        for (int tn = 0; tn < 4; tn++)
            #pragma unroll
            for (int r = 0; r < 4; r++) {
                float v = acc[tm][tn][r] + bias[tn];
                v = v > 0.f ? v : 0.f;
                t16[(wr * 16 + q * 4 + r) * 136 + wc * 64 + tn * 16 + li] = (bf16_t)v;
            }
        __syncthreads();
        long grow = row0 + ((rr >> 4) * 64) + tm * 16 + (rr & 15);
        if (grow < NROWS) {
            bf16x8 v0 = *(const bf16x8*)&t16[rr * 136 + cc * 16];
            bf16x8 v1 = *(const bf16x8*)&t16[rr * 136 + cc * 16 + 8];
            *(bf16x8*)&hh[grow * 512 + col0 + cc * 16] = v0;
            *(bf16x8*)&hh[grow * 512 + col0 + cc * 16 + 8] = v1;
        }
        __syncthreads();
    }
}

// ---------------- GEMM2: 128 rows x 256 cols per block, fused att + cls ----------------
// grid = 782: blocks [0,391) = col-half 0 (+cls), [391,782) = col-half 1.
// Araw accumulated via atomicAdd (pre-zeroed).
__global__ __launch_bounds__(256, 2) void k_gemm2(
        const bf16_t* __restrict__ hh, const bf16_t* __restrict__ permB2,
        const bf16_t* __restrict__ clsWb,
        const float* __restrict__ aab, const float* __restrict__ abb,
        const float* __restrict__ acW, const float* __restrict__ acb,
        const float* __restrict__ clsb,
        float* __restrict__ Araw, float* __restrict__ inst) {
    // A0 @0 (8K), A1 @8192, B0 @16384 (16K), B1 @32768 (16K), clsW @49152 (2K)
    __shared__ __align__(16) char smem[51200];
    bf16_t* clsLds = (bf16_t*)(smem + 49152);

    const int tid = threadIdx.x;
    const int w = tid >> 6, l = tid & 63, q = l >> 4, li = l & 15;
    const int wr = w >> 1, wc = w & 1;
    const int b = blockIdx.x;
    const int half = (b >= 391) ? 1 : 0;
    const long row0 = (long)(half ? b - 391 : b) * 128;

    f32x4 acc[4][8];
    #pragma unroll
    for (int a = 0; a < 4; a++)
        #pragma unroll
        for (int c = 0; c < 8; c++) acc[a][c] = (f32x4)0.0f;
    float cls0[4] = {0.f,0.f,0.f,0.f}, cls1[4] = {0.f,0.f,0.f,0.f};

    // ---- prologue ----
    if (tid < 128) cp16(smem + 49152 + tid * 16, clsWb + tid * 8);
    #pragma unroll
    for (int j = 0; j < 4; j++) {
        int s = j * 256 + tid;
        cp16(smem + 16384 + s * 16, permB2 + (s >> 8) * 4096 + (half * 256 + (s & 255)) * 8);
    }
    #pragma unroll
    for (int j = 0; j < 2; j++) {
        int s = j * 256 + tid;
        cp16(smem + s * 16, hh + (row0 + (s >> 2)) * 512 + (s & 3) * 8);
    }
    __syncthreads();

    for (int kt = 0; kt < 16; kt++) {
        const int cur = kt & 1, nxt = cur ^ 1;
        if (kt < 15) {
            const bf16_t* gb = permB2 + (long)(kt + 1) * 16384;
            #pragma unroll
            for (int j = 0; j < 4; j++) {
                int s = j * 256 + tid;
                cp16(smem + 16384 + nxt * 16384 + s * 16, gb + (s >> 8) * 4096 + (half * 256 + (s & 255)) * 8);
            }
            #pragma unroll
            for (int j = 0; j < 2; j++) {
                int s = j * 256 + tid;
                cp16(smem + nxt * 8192 + s * 16, hh + (row0 + (s >> 2)) * 512 + (kt + 1) * 32 + (s & 3) * 8);
            }
        }
        const bf16_t* Ab = (const bf16_t*)(smem + cur * 8192);       // elem: row*32 + c
        const bf16_t* Bb = (const bf16_t*)(smem + 16384 + cur * 16384); // elem: q*2048 + col*8
        bf16x8 bfr[8];
        #pragma unroll
        for (int tn = 0; tn < 8; tn++)
            bfr[tn] = *(const bf16x8*)(Bb + q * 2048 + (wc * 128 + tn * 16 + li) * 8);
        bf16x8 afr[4];
        #pragma unroll
        for (int tm = 0; tm < 4; tm++)
            afr[tm] = *(const bf16x8*)(Ab + (wr * 64 + tm * 16 + li) * 32 + q * 8);
        #pragma unroll
        for (int tm = 0; tm < 4; tm++)
            #pragma unroll
            for (int tn = 0; tn < 8; tn++)
                acc[tm][tn] = __builtin_amdgcn_mfma_f32_16x16x32_bf16(afr[tm], bfr[tn], acc[tm][tn], 0, 0, 0);
        if (half == 0 && wc == (kt >> 3)) {
            bf16x8 w0 = *(const bf16x8*)(clsLds + kt * 32 + q * 8);
            bf16x8 w1 = *(const bf16x8*)(clsLds + 512 + kt * 32 + q * 8);
            #pragma unroll
            for (int tm = 0; tm < 4; tm++) {
                float s0 = 0.f, s1 = 0.f;
                #pragma unroll
                for (int jj = 0; jj < 8; jj++) {
                    float a = (float)afr[tm][jj];
                    s0 += a * (float)w0[jj];
                    s1 += a * (float)w1[jj];
                }
                cls0[tm] += s0; cls1[tm] += s1;
            }
        }
        __syncthreads();
    }

    // ---- epilogue ----
    float (*apart)[2]     = (float (*)[2])smem;            // [128][2] @0 (1 KB)
    float (*cpart)[64][2] = (float (*)[64][2])(smem + 2048); // [4][64][2] @2048 (2 KB)

    float sum_mr[4][4];
    #pragma unroll
    for (int a = 0; a < 4; a++)
        #pragma unroll
        for (int c = 0; c < 4; c++) sum_mr[a][c] = 0.f;
    #pragma unroll
    for (int p = 0; p < 4; p++) {
        int j = (half * 8 + wc * 4 + p) * 16 + li;
        float ab_ = aab[j], bb_ = abb[j], cw = acW[j];
        int tn_a = p * 2, tn_b = p * 2 + 1;
        #pragma unroll
        for (int tm = 0; tm < 4; tm++)
            #pragma unroll
            for (int r = 0; r < 4; r++) {
                float av = tanhf(acc[tm][tn_a][r] + ab_);
                float bv = acc[tm][tn_b][r] + bb_;
                bv = 1.f / (1.f + expf(-bv));
                sum_mr[tm][r] += av * bv * cw;
            }
    }
    #pragma unroll
    for (int tm = 0; tm < 4; tm++)
        #pragma unroll
        for (int r = 0; r < 4; r++) {
            float v = sum_mr[tm][r];
            v += __shfl_xor(v, 1); v += __shfl_xor(v, 2);
            v += __shfl_xor(v, 4); v += __shfl_xor(v, 8);
            if (li == 0) apart[wr * 64 + tm * 16 + q * 4 + r][wc] = v;
        }
    if (half == 0) {
        #pragma unroll
        for (int tm = 0; tm < 4; tm++) {
            cls0[tm] += __shfl_xor(cls0[tm], 16); cls0[tm] += __shfl_xor(cls0[tm], 32);
            cls1[tm] += __shfl_xor(cls1[tm], 16); cls1[tm] += __shfl_xor(cls1[tm], 32);
            if (q == 0) {
                cpart[w][tm * 16 + li][0] = cls0[tm];
                cpart[w][tm * 16 + li][1] = cls1[tm];
            }
        }
    }
    __syncthreads();
    if (tid < 128) {
        float s = apart[tid][0] + apart[tid][1];
        if (half == 0) s += acb[0];
        long row = row0 + tid;
        if (row < NROWS) atomicAdd(Araw + row, s);
    }
    if (half == 0) {
        int r = tid >> 1, c = tid & 1;
        float s = clsb[c] + cpart[2 * (r >> 6)][r & 63][c] + cpart[2 * (r >> 6) + 1][r & 63][c];
        long row = row0 + r;
        if (row < NROWS) inst[row * 2 + c] = s;
    }
}

// ---------------- top-8/bottom-8 partials: 8 blocks (4 quarters x 2 passes) ----------------
__global__ void k_topk_part(const float* __restrict__ scores,
                            float* __restrict__ candV, int* __restrict__ candI,
                            float* __restrict__ sums) {
    __shared__ float cv[4096];
    __shared__ int   ci[4096];
    int tid = threadIdx.x;        // 512
    int p = blockIdx.x;           // 0..7
    int pass = p & 1, rq = p >> 1;
    if (p == 0 && tid == 0) { sums[0] = 0.f; sums[1] = 0.f; sums[2] = 0.f; }
    float sign = pass ? -1.f : 1.f;
    int lo = rq * 12500, hi = lo + 12500;
    float tv[8]; int ti[8];
    #pragma unroll
    for (int k = 0; k < 8; k++) { tv[k] = -1e30f; ti[k] = 0x7fffffff; }
    for (int i = lo + tid; i < hi; i += 512) {
        float v = sign * scores[i];
        if (v > tv[7] || (v == tv[7] && i < ti[7])) {
            int k = 7;
            while (k > 0 && (v > tv[k-1] || (v == tv[k-1] && i < ti[k-1]))) {
                tv[k] = tv[k-1]; ti[k] = ti[k-1]; k--;
            }
            tv[k] = v; ti[k] = i;
        }
    }
    #pragma unroll
    for (int k = 0; k < 8; k++) { cv[tid * 8 + k] = tv[k]; ci[tid * 8 + k] = ti[k]; }
    __syncthreads();
    if (tid < 64) {
        float mv[8]; int mi[8];
        #pragma unroll
        for (int k = 0; k < 8; k++) { mv[k] = -1e30f; mi[k] = 0x7fffffff; }
        for (int i = 0; i < 64; i++) {
            int slot = tid * 64 + ((i + tid) & 63);   // lane-rotated: spread banks
            float v = cv[slot]; int idx = ci[slot];
            #pragma unroll
            for (int k = 0; k < 8; k++) {
                bool bt = (v > mv[k]) || (v == mv[k] && idx < mi[k]);
                float nv = bt ? v : mv[k];  int ni = bt ? idx : mi[k];
                float ov = bt ? mv[k] : v;  int oi = bt ? mi[k] : idx;
                mv[k] = nv; mi[k] = ni; v = ov; idx = oi;
            }
        }
        for (int r = 0; r < 8; r++) {
            float bv = mv[0]; int bi = mi[0]; int bs = tid;
            for (int m = 1; m < 64; m <<= 1) {
                float ov = __shfl_xor(bv, m); int oi = __shfl_xor(bi, m); int os = __shfl_xor(bs, m);
                if (ov > bv || (ov == bv && oi < bi)) { bv = ov; bi = oi; bs = os; }
            }
            if (tid == 0) {
                candV[pass * 32 + rq * 8 + r] = bv;
                candI[pass * 32 + rq * 8 + r] = bi;
            }
            if (tid == bs) {
                #pragma unroll
                for (int k = 0; k < 7; k++) { mv[k] = mv[k+1]; mi[k] = mi[k+1]; }
                mv[7] = -1e30f; mi[7] = 0x7fffffff;
            }
        }
    }
}

// ---------------- softmax-weighted sums (max = best quarter top-1) ----------------
__global__ void k_sum(const float* __restrict__ Araw, const float* __restrict__ inst,
                      const float* __restrict__ candV, float* sums) {
    __shared__ float r0[4], r1[4], r2[4];
    int tid = threadIdx.x;
    float mx = -1e30f;
    #pragma unroll
    for (int p = 0; p < 4; p++) mx = fmaxf(mx, candV[p * 8]);
    float se = 0.f, s0 = 0.f, s1 = 0.f;
    for (int i = blockIdx.x * 256 + tid; i < NROWS; i += 32768) {
        float e = expf(Araw[i] - mx);
        se += e; s0 += inst[2 * i] * e; s1 += inst[2 * i + 1] * e;
    }
    for (int s = 1; s < 64; s <<= 1) {
        se += __shfl_xor(se, s); s0 += __shfl_xor(s0, s); s1 += __shfl_xor(s1, s);
    }
    if ((tid & 63) == 0) { r0[tid >> 6] = se; r1[tid >> 6] = s0; r2[tid >> 6] = s1; }
    __syncthreads();
    if (tid == 0) {
        atomicAdd(&sums[0], r0[0] + r0[1] + r0[2] + r0[3]);
        atomicAdd(&sums[1], r1[0] + r1[1] + r1[2] + r1[3]);
        atomicAdd(&sums[2], r2[0] + r2[1] + r2[2] + r2[3]);
    }
}

// ---------------- finalize: merge 32+32 candidates, preds + instance_loss ----------------
__global__ void k_fin(const bf16_t* __restrict__ hh,
                      const float* __restrict__ candV, const int* __restrict__ candI,
                      const float* __restrict__ sums, const float* __restrict__ instW,
                      const float* __restrict__ instb, float* __restrict__ dout) {
    __shared__ int mid[16];
    __shared__ float lg[16][2];
    int tid = threadIdx.x;          // 256
    int wv = tid >> 6, l = tid & 63;
    if (wv < 2) {
        float v; int idx;
        if (l < 32) { v = candV[wv * 32 + l]; idx = candI[wv * 32 + l]; }
        else        { v = -1e30f; idx = 0x7fffffff; }
        for (int r = 0; r < 8; r++) {
            float bv = v; int bi = idx; int bs = l;
            for (int m = 1; m < 64; m <<= 1) {
                float ov = __shfl_xor(bv, m); int oi = __shfl_xor(bi, m); int os = __shfl_xor(bs, m);
                if (ov > bv || (ov == bv && oi < bi)) { bv = ov; bi = oi; bs = os; }
            }
            if (l == 0) mid[wv * 8 + r] = bi;
            if (l == bs) { v = -1e30f; idx = 0x7fffffff; }
        }
    }
    __syncthreads();
    int r = tid >> 4, li = tid & 15;
    int id = mid[r];
    const bf16_t* hp = hh + (long)id * 512;
    float p0 = 0.f, p1 = 0.f;
    for (int k = li * 32; k < li * 32 + 32; k++) {
        float h = (float)hp[k];
        p0 += h * instW[k]; p1 += h * instW[512 + k];
    }
    for (int m = 1; m < 16; m <<= 1) { p0 += __shfl_xor(p0, m); p1 += __shfl_xor(p1, m); }
    if (li == 0) { lg[r][0] = p0 + instb[0]; lg[r][1] = p1 + instb[1]; }
    __syncthreads();
    if (tid == 0) {
        float loss = 0.f;
        for (int r2 = 0; r2 < 16; r2++) {
            float l0 = lg[r2][0], l1 = lg[r2][1];
            float mx = fmaxf(l0, l1);
            float lse = mx + logf(expf(l0 - mx) + expf(l1 - mx));
            float lt = (r2 < 8) ? l1 : l0;
            loss += (lse - lt);
        }
        dout[150002] = loss / 16.f;
        float se = sums[0];
        dout[0] = sums[1] / se;
        dout[1] = sums[2] / se;
    }
}

extern "C" void kernel_launch(void* const* d_in, const int* in_sizes, int n_in,
                              void* d_out, int out_size, void* d_ws, size_t ws_size,
                              hipStream_t stream) {
    const float* h   = (const float*)d_in[0];
    const float* fcW = (const float*)d_in[1];
    const float* fcb = (const float*)d_in[2];
    const float* aaW = (const float*)d_in[3];
    const float* aab = (const float*)d_in[4];
    const float* abW = (const float*)d_in[5];
    const float* abb = (const float*)d_in[6];
    const float* acW = (const float*)d_in[7];
    const float* acb = (const float*)d_in[8];
    const float* clW = (const float*)d_in[9];
    const float* clb = (const float*)d_in[10];
    const float* inW = (const float*)d_in[11];
    const float* inb = (const float*)d_in[12];
    float* out = (float*)d_out;

    char* ws = (char*)d_ws;
    bf16_t* hh      = (bf16_t*)(ws);                       // 51,200,000 B
    bf16_t* permW1  = (bf16_t*)(ws + 51200000);            // 1,048,576 B
    bf16_t* permB2  = (bf16_t*)(ws + 52248576);            // 524,288 B
    bf16_t* clsWb   = (bf16_t*)(ws + 52772864);            // 2,048 B
    float*  candV   = (float*) (ws + 52774912);            // 256 B
    int*    candI   = (int*)   (ws + 52775424);            // 256 B
    float*  sums    = (float*) (ws + 52775936);            // 16 B

    float* inst = out + 2;
    float* Araw = out + 2 + 100000;

    k_convert<<<772, 256, 0, stream>>>(fcW, aaW, abW, clW, permW1, permB2, clsWb);
    k_gemm1<<<1568, 256, 0, stream>>>(h, permW1, fcb, hh);
    hipMemsetAsync(Araw, 0, NROWS * sizeof(float), stream);
    k_gemm2<<<782, 256, 0, stream>>>(hh, permB2, clsWb, aab, abb, acW, acb, clb, Araw, inst);
    k_topk_part<<<8, 512, 0, stream>>>(Araw, candV, candI, sums);
    k_sum<<<128, 256, 0, stream>>>(Araw, inst, candV, sums);
    k_fin<<<1, 256, 0, stream>>>(hh, candV, candI, sums, inW, inb, out);
}